// Round 14
// baseline (495.748 us; speedup 1.0000x reference)
//
#include <hip/hip_runtime.h>

typedef __attribute__((ext_vector_type(8))) short s8x;   // 8 x bf16 (raw bits)
typedef __attribute__((ext_vector_type(4))) float f4x;
typedef unsigned short u16;
typedef unsigned int u32;

#define DEV static __device__ __forceinline__

DEV u16 f2b(float f) {
    union { float f; u32 u; } v; v.f = f;
    u32 r = v.u + 0x7FFFu + ((v.u >> 16) & 1u);
    return (u16)(r >> 16);
}

DEV float b2f(u16 x) {
    union { u32 u; float f; } v; v.u = (u32)x << 16;
    return v.f;
}

DEV u32 pk2(float lo, float hi) {   // v_cvt_pk_bf16_f32: low16=lo, high16=hi
    u32 r;
    asm("v_cvt_pk_bf16_f32 %0, %1, %2" : "=v"(r) : "v"(lo), "v"(hi));
    return r;
}

DEV float exp2_raw(float x) {       // D = 2^x (v_exp_f32 native semantics)
    float r;
    asm("v_exp_f32 %0, %1" : "=v"(r) : "v"(x));
    return r;
}

DEV void gload16(const void* g, void* lds) {
    __builtin_amdgcn_global_load_lds(
        (const __attribute__((address_space(1))) void*)g,
        (__attribute__((address_space(3))) void*)lds, 16, 0, 0);
}

#define GK 1024
#define BM 128
#define BN 128
#define BK 64

// ---------------- 8-phase GEMM core pieces (T2 swizzle, T3/T4 counted vmcnt, T5 setprio) ----
// Swizzle (both-sides, rule #21): LDS[row][cd] = G[row][cd ^ (row&7)]; read chunk = want ^ (row&7).

DEV void stage_unit(const u16* __restrict__ g, char* l, int tid) {
    // one 16KB unit = 128 rows x 128B; 512 threads x 2 x 16B
#pragma unroll
    for (int i = 0; i < 2; ++i) {
        int db = i * 8192 + tid * 16;
        int row = db >> 7;
        int cs = ((db >> 4) & 7) ^ (row & 7);
        gload16(g + (size_t)row * 1024 + cs * 8, l + db);
    }
}

DEV s8x lds_frag(const char* Lbase, int row, int kk, int lg) {
    int cb = (kk * 64 + lg * 16) ^ ((row & 7) << 4);
    return *(const s8x*)(Lbase + row * 128 + cb);
}

// ---------------- gemm8: C[M,N] = A[M,K] @ W[N,K]^T, 256x128 tile, 8 waves ----------------
// FLAGS: 1=RELU, 2=RES (bf16 residual add after relu), 4=WF (f32 out), 8=WB (bf16 out), 16=row-bias
template<int FLAGS, int NN>
__global__ __launch_bounds__(512, 2) void gemm8(
    const u16* __restrict__ A, const u16* __restrict__ W,
    const float* __restrict__ bias, const u16* __restrict__ res,
    float* __restrict__ outf, u16* __restrict__ outb, float scl)
{
    constexpr bool RELU = (FLAGS & 1) != 0;
    constexpr bool RES  = (FLAGS & 2) != 0;
    constexpr bool WF   = (FLAGS & 4) != 0;
    constexpr bool WB   = (FLAGS & 8) != 0;
    constexpr bool RBIA = (FLAGS & 16) != 0;

    __shared__ __attribute__((aligned(16))) u16 As[3][256 * 64];   // 96 KB
    __shared__ __attribute__((aligned(16))) u16 Bs[3][128 * 64];   // 48 KB

    const int tid = threadIdx.x, lane = tid & 63, wid = tid >> 6;
    const int l15 = lane & 15, lg = lane >> 4;
    const int wm = wid >> 1, wn = wid & 1;
    const int bm = blockIdx.x, bn = blockIdx.y;

    const u16* Ab = A + (size_t)bm * 256 * GK;
    const u16* Wb = W + (size_t)bn * 128 * GK;

    f4x acc[4][4];
#pragma unroll
    for (int i = 0; i < 4; ++i)
#pragma unroll
        for (int j = 0; j < 4; ++j) { f4x z = {0.f, 0.f, 0.f, 0.f}; acc[i][j] = z; }

    char* a0 = (char*)As[0]; char* a1 = (char*)As[1]; char* a2 = (char*)As[2];
    char* b0 = (char*)Bs[0]; char* b1 = (char*)Bs[1]; char* b2 = (char*)Bs[2];

    stage_unit(Ab + 0 * 64,                 a0,        tid);
    stage_unit(Ab + 128 * GK + 0 * 64,      a0 + 16384, tid);
    stage_unit(Wb + 0 * 64,                 b0,        tid);
    stage_unit(Ab + 1 * 64,                 a1,        tid);
    stage_unit(Ab + 128 * GK + 1 * 64,      a1 + 16384, tid);
    stage_unit(Wb + 1 * 64,                 b1,        tid);
    asm volatile("s_waitcnt vmcnt(6)" ::: "memory");
    __builtin_amdgcn_s_barrier();

    for (int t = 0; t < 16; ++t) {
        const bool st = (t < 14);
        s8x bfr[4][2], afr[2][2];
#pragma unroll
        for (int ni = 0; ni < 4; ++ni)
#pragma unroll
            for (int kk = 0; kk < 2; ++kk)
                bfr[ni][kk] = lds_frag(b0, wn * 64 + ni * 16 + l15, kk, lg);
#pragma unroll
        for (int mi = 0; mi < 2; ++mi)
#pragma unroll
            for (int kk = 0; kk < 2; ++kk)
                afr[mi][kk] = lds_frag(a0, wm * 64 + mi * 16 + l15, kk, lg);
        if (st) {
            stage_unit(Ab + (t + 2) * 64,            a2,         tid);
            stage_unit(Ab + 128 * GK + (t + 2) * 64, a2 + 16384, tid);
        }
        __builtin_amdgcn_s_barrier();
        asm volatile("s_waitcnt lgkmcnt(0)" ::: "memory");
        __builtin_amdgcn_sched_barrier(0);
        __builtin_amdgcn_s_setprio(1);
#pragma unroll
        for (int kk = 0; kk < 2; ++kk)
#pragma unroll
            for (int mi = 0; mi < 2; ++mi)
#pragma unroll
                for (int ni = 0; ni < 4; ++ni)
                    acc[mi][ni] = __builtin_amdgcn_mfma_f32_16x16x32_bf16(afr[mi][kk], bfr[ni][kk], acc[mi][ni], 0, 0, 0);
        __builtin_amdgcn_s_setprio(0);
        __builtin_amdgcn_s_barrier();

        s8x afr2[2][2];
#pragma unroll
        for (int mi = 0; mi < 2; ++mi)
#pragma unroll
            for (int kk = 0; kk < 2; ++kk)
                afr2[mi][kk] = lds_frag(a0, wm * 64 + (mi + 2) * 16 + l15, kk, lg);
        if (st) stage_unit(Wb + (t + 2) * 64, b2, tid);
        __builtin_amdgcn_s_barrier();
        asm volatile("s_waitcnt lgkmcnt(0)" ::: "memory");
        __builtin_amdgcn_sched_barrier(0);
        __builtin_amdgcn_s_setprio(1);
#pragma unroll
        for (int kk = 0; kk < 2; ++kk)
#pragma unroll
            for (int mi = 0; mi < 2; ++mi)
#pragma unroll
                for (int ni = 0; ni < 4; ++ni)
                    acc[mi + 2][ni] = __builtin_amdgcn_mfma_f32_16x16x32_bf16(afr2[mi][kk], bfr[ni][kk], acc[mi + 2][ni], 0, 0, 0);
        __builtin_amdgcn_s_setprio(0);
        if (st) asm volatile("s_waitcnt vmcnt(6)" ::: "memory");
        else    asm volatile("s_waitcnt vmcnt(0)" ::: "memory");
        __builtin_amdgcn_s_barrier();

        char* tA = a0; a0 = a1; a1 = a2; a2 = tA;
        char* tB = b0; b0 = b1; b1 = b2; b2 = tB;
    }

#pragma unroll
    for (int ni = 0; ni < 4; ++ni) {
        int gcol = bn * 128 + wn * 64 + ni * 16 + l15;
        float bvc = RBIA ? 0.f : bias[gcol];
#pragma unroll
        for (int mi = 0; mi < 4; ++mi) {
            int grow0 = bm * 256 + wm * 64 + mi * 16 + lg * 4;
#pragma unroll
            for (int r = 0; r < 4; ++r) {
                float bv = RBIA ? bias[grow0 + r] : bvc;
                float v = (acc[mi][ni][r] + bv) * scl;
                if (RELU) v = fmaxf(v, 0.f);
                size_t oidx = (size_t)(grow0 + r) * NN + gcol;
                if (RES) v += b2f(res[oidx]);
                if (WF) outf[oidx] = v;
                if (WB) outb[oidx] = f2b(v);
            }
        }
    }
}

// ---------------- gemm_qk256: z=2-paired 256x256-tile GEMM (Q and K projections) ----------------
__global__ __launch_bounds__(512, 2) void gemm_qk256(
    const u16* __restrict__ A0p, const u16* __restrict__ W0p, const float* __restrict__ b0p,
    u16* __restrict__ o0p, float s0,
    const u16* __restrict__ A1p, const u16* __restrict__ W1p, const float* __restrict__ b1p,
    u16* __restrict__ o1p, float s1)
{
    const int z = blockIdx.z;
    const u16* A = z ? A1p : A0p;
    const u16* W = z ? W1p : W0p;
    const float* bias = z ? b1p : b0p;
    u16* outb = z ? o1p : o0p;
    const float scl = z ? s1 : s0;

    __shared__ __attribute__((aligned(16))) u16 As[3][256 * 64];   // 96 KB
    __shared__ __attribute__((aligned(16))) u16 Bs[2][256 * 64];   // 64 KB

    const int tid = threadIdx.x, lane = tid & 63, wid = tid >> 6;
    const int l15 = lane & 15, lg = lane >> 4;
    const int wm = wid >> 2;
    const int wn = wid & 3;
    const int bm = blockIdx.x, bn = blockIdx.y;

    const u16* Ab = A + (size_t)bm * 256 * GK;
    const u16* Wb = W + (size_t)bn * 256 * GK;

    f4x acc[8][4];
#pragma unroll
    for (int i = 0; i < 8; ++i)
#pragma unroll
        for (int j = 0; j < 4; ++j) { f4x zz = {0.f, 0.f, 0.f, 0.f}; acc[i][j] = zz; }

    char* a0 = (char*)As[0]; char* a1 = (char*)As[1]; char* a2 = (char*)As[2];
    char* b0 = (char*)Bs[0]; char* b1 = (char*)Bs[1];

    stage_unit(Ab + 0 * 64,            a0,         tid);
    stage_unit(Ab + 128 * GK + 0 * 64, a0 + 16384, tid);
    stage_unit(Wb + 0 * 64,            b0,         tid);
    stage_unit(Wb + 128 * GK + 0 * 64, b0 + 16384, tid);
    stage_unit(Ab + 1 * 64,            a1,         tid);
    stage_unit(Ab + 128 * GK + 1 * 64, a1 + 16384, tid);
    asm volatile("s_waitcnt vmcnt(4)" ::: "memory");
    __builtin_amdgcn_s_barrier();

    const char* aW = nullptr;
    const char* bW = nullptr;
    for (int t = 0; t < 16; ++t) {
        aW = a0 + wm * 16384;
        bW = b0 + (wn >> 1) * 16384;
        const int brow0 = (wn & 1) * 64;

        s8x bfr[4][2], afr[4][2];
#pragma unroll
        for (int ni = 0; ni < 4; ++ni)
#pragma unroll
            for (int kk = 0; kk < 2; ++kk)
                bfr[ni][kk] = lds_frag(bW, brow0 + ni * 16 + l15, kk, lg);
#pragma unroll
        for (int mi = 0; mi < 4; ++mi)
#pragma unroll
            for (int kk = 0; kk < 2; ++kk)
                afr[mi][kk] = lds_frag(aW, mi * 16 + l15, kk, lg);
        if (t + 1 < 16) {
            stage_unit(Wb + (t + 1) * 64,            b1,         tid);
            stage_unit(Wb + 128 * GK + (t + 1) * 64, b1 + 16384, tid);
        }
        __builtin_amdgcn_s_barrier();
        asm volatile("s_waitcnt lgkmcnt(0)" ::: "memory");
        __builtin_amdgcn_sched_barrier(0);
        __builtin_amdgcn_s_setprio(1);
#pragma unroll
        for (int kk = 0; kk < 2; ++kk)
#pragma unroll
            for (int mi = 0; mi < 4; ++mi)
#pragma unroll
                for (int ni = 0; ni < 4; ++ni)
                    acc[mi][ni] = __builtin_amdgcn_mfma_f32_16x16x32_bf16(afr[mi][kk], bfr[ni][kk], acc[mi][ni], 0, 0, 0);
        __builtin_amdgcn_s_setprio(0);
        __builtin_amdgcn_s_barrier();

        s8x afr2[4][2];
#pragma unroll
        for (int mi = 0; mi < 4; ++mi)
#pragma unroll
            for (int kk = 0; kk < 2; ++kk)
                afr2[mi][kk] = lds_frag(aW, (mi + 4) * 16 + l15, kk, lg);
        if (t + 2 < 16) {
            stage_unit(Ab + (t + 2) * 64,            a2,         tid);
            stage_unit(Ab + 128 * GK + (t + 2) * 64, a2 + 16384, tid);
        }
        __builtin_amdgcn_s_barrier();
        asm volatile("s_waitcnt lgkmcnt(0)" ::: "memory");
        __builtin_amdgcn_sched_barrier(0);
        __builtin_amdgcn_s_setprio(1);
#pragma unroll
        for (int kk = 0; kk < 2; ++kk)
#pragma unroll
            for (int mi = 0; mi < 4; ++mi)
#pragma unroll
                for (int ni = 0; ni < 4; ++ni)
                    acc[mi + 4][ni] = __builtin_amdgcn_mfma_f32_16x16x32_bf16(afr2[mi][kk], bfr[ni][kk], acc[mi + 4][ni], 0, 0, 0);
        __builtin_amdgcn_s_setprio(0);

        if (t <= 13)      asm volatile("s_waitcnt vmcnt(4)" ::: "memory");
        else if (t == 14) asm volatile("s_waitcnt vmcnt(0)" ::: "memory");
        __builtin_amdgcn_s_barrier();

        char* tA = a0; a0 = a1; a1 = a2; a2 = tA;
        char* tB = b0; b0 = b1; b1 = tB;
    }

#pragma unroll
    for (int ni = 0; ni < 4; ++ni) {
        int gcol = bn * 256 + wn * 64 + ni * 16 + l15;
        float bvc = bias[gcol];
#pragma unroll
        for (int mi = 0; mi < 8; ++mi) {
            int grow0 = bm * 256 + wm * 128 + mi * 16 + lg * 4;
#pragma unroll
            for (int r = 0; r < 4; ++r) {
                float v = (acc[mi][ni][r] + bvc) * scl;
                outb[(size_t)(grow0 + r) * 1024 + gcol] = f2b(v);
            }
        }
    }
}

// ---- z-batched 2-phase variant (weight-prep only): out = f2b((acc + bias) * scl) ----
__global__ __launch_bounds__(256) void gemm_z2(
    const u16* __restrict__ A0, const u16* __restrict__ W0, const float* __restrict__ b0,
    u16* __restrict__ o0, float s0,
    const u16* __restrict__ A1, const u16* __restrict__ W1, const float* __restrict__ b1,
    u16* __restrict__ o1, float s1)
{
    const int z = blockIdx.z;
    const u16* A = z ? A1 : A0;
    const u16* W = z ? W1 : W0;
    const float* bias = z ? b1 : b0;
    u16* outb = z ? o1 : o0;
    const float scl = z ? s1 : s0;

    __shared__ __attribute__((aligned(16))) u16 As[2][BM * BK];
    __shared__ __attribute__((aligned(16))) u16 Bs[2][BN * BK];

    const int tid  = threadIdx.x;
    const int lane = tid & 63;
    const int wid  = tid >> 6;
    const int wr = wid >> 1, wc = wid & 1;
    const int bm = blockIdx.x, bn = blockIdx.y;
    const int l15 = lane & 15;
    const int lg  = lane >> 4;

    const u16* Ab = A + (size_t)bm * BM * GK;
    const u16* Wb = W + (size_t)bn * BN * GK;

    const int prow = tid >> 3;
    const int pcol = (tid & 7) * 8;

    f4x acc[4][4];
#pragma unroll
    for (int i = 0; i < 4; ++i)
#pragma unroll
        for (int j = 0; j < 4; ++j) { f4x z_ = {0.f, 0.f, 0.f, 0.f}; acc[i][j] = z_; }

#pragma unroll
    for (int c = 0; c < 4; ++c) {
        int row = c * 32 + prow;
        gload16(Ab + (size_t)row * GK + pcol, &As[0][row * BK + pcol]);
    }
#pragma unroll
    for (int c = 0; c < 4; ++c) {
        int row = c * 32 + prow;
        gload16(Wb + (size_t)row * GK + pcol, &Bs[0][row * BK + pcol]);
    }

    const int nkt = GK / BK;
    int cur = 0;
    for (int kt = 0; kt < nkt; ++kt) {
        __syncthreads();
        if (kt + 1 < nkt) {
            const u16* Ak = Ab + (kt + 1) * BK;
            const u16* Wk = Wb + (kt + 1) * BK;
#pragma unroll
            for (int c = 0; c < 4; ++c) {
                int row = c * 32 + prow;
                gload16(Ak + (size_t)row * GK + pcol, &As[cur ^ 1][row * BK + pcol]);
            }
#pragma unroll
            for (int c = 0; c < 4; ++c) {
                int row = c * 32 + prow;
                gload16(Wk + (size_t)row * GK + pcol, &Bs[cur ^ 1][row * BK + pcol]);
            }
        }
        const u16* Ac = As[cur];
        const u16* Bc = Bs[cur];
#pragma unroll
        for (int kk = 0; kk < 2; ++kk) {
            s8x a[4], b[4];
#pragma unroll
            for (int mi = 0; mi < 4; ++mi)
                a[mi] = *(const s8x*)(Ac + (wr * 64 + mi * 16 + l15) * BK + kk * 32 + lg * 8);
#pragma unroll
            for (int ni = 0; ni < 4; ++ni)
                b[ni] = *(const s8x*)(Bc + (wc * 64 + ni * 16 + l15) * BK + kk * 32 + lg * 8);
#pragma unroll
            for (int mi = 0; mi < 4; ++mi)
#pragma unroll
                for (int ni = 0; ni < 4; ++ni)
                    acc[mi][ni] = __builtin_amdgcn_mfma_f32_16x16x32_bf16(a[mi], b[ni], acc[mi][ni], 0, 0, 0);
        }
        cur ^= 1;
    }

#pragma unroll
    for (int ni = 0; ni < 4; ++ni) {
        int gcol = bn * BN + wc * 64 + ni * 16 + l15;
        float bvc = bias[gcol];
#pragma unroll
        for (int mi = 0; mi < 4; ++mi) {
            int grow0 = bm * BM + wr * 64 + mi * 16 + lg * 4;
#pragma unroll
            for (int r = 0; r < 4; ++r) {
                float v = (acc[mi][ni][r] + bvc) * scl;
                outb[(size_t)(grow0 + r) * 1024 + gcol] = f2b(v);
            }
        }
    }
}

// ---------------- Attention v10: v9 + in-register P redistribution (no Ps LDS) ----------------
// LDS 48.25KB -> 3 blocks/CU. P[k][q] (C-layout) -> A-frag via 16 shfl + 8 selects:
// target lane (lg,l15) takes pw[2kk+(lg>>1)][h] from lanes l15+(lg&1)*32 (+16).
__global__ __launch_bounds__(512) void attn_kernel(
    const u16* __restrict__ Qm, const u16* __restrict__ Km, const u16* __restrict__ Vt,
    const u32* __restrict__ maskw, const u32* __restrict__ rowfl,
    u16* __restrict__ Om)
{
    const int bh = blockIdx.x;
    const int b  = bh >> 4;
    const int h  = bh & 15;
    const int qt = blockIdx.y;
    const int tid = threadIdx.x, lane = tid & 63, wid = tid >> 6;
    const int l15 = lane & 15, lg = lane >> 4;

    __shared__ __attribute__((aligned(16))) u16 Ks[3][64 * 64];   // 24 KB
    __shared__ __attribute__((aligned(16))) u16 Vs[3][64 * 64];   // 24 KB
    __shared__ int anymask;

    const size_t rowbase = (size_t)b * 1024;
    const int hoff = h * 64;

    if (tid == 0) anymask = 0;

    const int so   = tid * 16;
    const int srow = so >> 7;
    const int sch  = ((so >> 4) & 7) ^ (srow & 7);

    const u16* Kbase = Km + rowbase * 1024 + hoff + (size_t)srow * 1024 + sch * 8;
    const u16* Vbase = Vt + (size_t)(hoff + srow) * 8192 + b * 1024 + sch * 8;

    // prologue: stage tiles 0 and 1
    gload16(Kbase + 0 * 64 * 1024, (char*)Ks[0] + so);
    gload16(Vbase + 0 * 64,        (char*)Vs[0] + so);
    gload16(Kbase + 1 * 64 * 1024, (char*)Ks[1] + so);
    gload16(Vbase + 1 * 64,        (char*)Vs[1] + so);

    const int qrow = qt * 128 + wid * 16 + l15;
    s8x qf[2];
#pragma unroll
    for (int kk = 0; kk < 2; ++kk)
        qf[kk] = *(const s8x*)(Qm + (rowbase + qrow) * 1024 + hoff + kk * 32 + lg * 8);

    __syncthreads();   // anymask = 0 visible
    if (tid < 128) {
        if (rowfl[rowbase + qt * 128 + tid]) atomicOr(&anymask, 1);
    }

    f4x o[4];
#pragma unroll
    for (int d = 0; d < 4; ++d) { f4x z = {0.f, 0.f, 0.f, 0.f}; o[d] = z; }
    f4x osum = {0.f, 0.f, 0.f, 0.f};
    const s8x ones = {(short)0x3F80, (short)0x3F80, (short)0x3F80, (short)0x3F80,
                      (short)0x3F80, (short)0x3F80, (short)0x3F80, (short)0x3F80};

    asm volatile("s_waitcnt vmcnt(0)" ::: "memory");   // tiles 0,1 + qf + rowfl done
    __syncthreads();                                    // staging + atomicOr visible
    const int am = anymask;

    const int src0 = l15 + (lg & 1) * 32;   // source lane for j=0..3
    const int src1 = src0 + 16;             // source lane for j=4..7
    const bool selhi = (lg >> 1) != 0;      // pick pw[n+1] vs pw[n]

#pragma unroll
    for (int kt = 0; kt < 16; ++kt) {
        const char* kc = (const char*)Ks[kt % 3];
        const char* vc = (const char*)Vs[kt % 3];
        // T14/T3: issue tile kt+2 staging into the buffer freed at kt-1's barrier
        if (kt + 2 < 16) {
            gload16(Kbase + (size_t)(kt + 2) * 64 * 1024, (char*)Ks[(kt + 2) % 3] + so);
            gload16(Vbase + (kt + 2) * 64,                (char*)Vs[(kt + 2) % 3] + so);
        }

        // swapped QK^T: C[k][q]; scores in log2 units (Q prescaled by log2e/8)
        f4x sc[4];
#pragma unroll
        for (int ni = 0; ni < 4; ++ni) { f4x z = {0.f, 0.f, 0.f, 0.f}; sc[ni] = z; }
        __builtin_amdgcn_s_setprio(1);
#pragma unroll
        for (int kk = 0; kk < 2; ++kk) {
#pragma unroll
            for (int ni = 0; ni < 4; ++ni) {
                int row = ni * 16 + l15;
                int cb  = (kk * 64 + lg * 16) ^ ((row & 7) << 4);
                s8x kf = *(const s8x*)(kc + row * 128 + cb);
                sc[ni] = __builtin_amdgcn_mfma_f32_16x16x32_bf16(kf, qf[kk], sc[ni], 0, 0, 0);
            }
        }
        __builtin_amdgcn_s_setprio(0);

        if (am) {
            int qg = qt * 128 + wid * 16 + l15;
#pragma unroll
            for (int ni = 0; ni < 4; ++ni)
#pragma unroll
                for (int r = 0; r < 4; ++r) {
                    int kcol = kt * 64 + ni * 16 + lg * 4 + r;
                    u32 wb_ = maskw[(rowbase + qg) * 32 + (kcol >> 5)];
                    if (wb_ & (1u << (kcol & 31))) sc[ni][r] = -1e9f;
                }
        }

        // p = 2^s raw (no clip; masked -1e9 underflows to 0); pack pairs
        u32 pw[4][2];
#pragma unroll
        for (int ni = 0; ni < 4; ++ni) {
#pragma unroll
            for (int r = 0; r < 4; ++r)
                sc[ni][r] = exp2_raw(sc[ni][r]);
            pw[ni][0] = pk2(sc[ni][0], sc[ni][1]);
            pw[ni][1] = pk2(sc[ni][2], sc[ni][3]);
        }

        // in-register redistribution: pa[kk] word w from src lanes, value-select by lg>>1
        s8x pa[2];
#pragma unroll
        for (int kk = 0; kk < 2; ++kk) {
            u32 w[4];
#pragma unroll
            for (int hh = 0; hh < 2; ++hh) {
                u32 x0 = __shfl(pw[2 * kk][hh],     src0);
                u32 x1 = __shfl(pw[2 * kk + 1][hh], src0);
                w[hh] = selhi ? x1 : x0;
                u32 y0 = __shfl(pw[2 * kk][hh],     src1);
                u32 y1 = __shfl(pw[2 * kk + 1][hh], src1);
                w[2 + hh] = selhi ? y1 : y0;
            }
            union { u32 u[4]; s8x v; } cvt;
            cvt.u[0] = w[0]; cvt.u[1] = w[1]; cvt.u[2] = w[2]; cvt.u[3] = w[3];
            pa[kk] = cvt.v;
        }

        __builtin_amdgcn_s_setprio(1);
        // denominator on the matrix pipe: osum[q] += sum_k P[q][k]
#pragma unroll
        for (int kk = 0; kk < 2; ++kk)
            osum = __builtin_amdgcn_mfma_f32_16x16x32_bf16(pa[kk], ones, osum, 0, 0, 0);
#pragma unroll
        for (int dt = 0; dt < 4; ++dt)
#pragma unroll
            for (int kk = 0; kk < 2; ++kk) {
                int row = dt * 16 + l15;
                int cb  = (kk * 64 + lg * 16) ^ ((row & 7) << 4);
                s8x vf = *(const s8x*)(vc + row * 128 + cb);
                o[dt] = __builtin_amdgcn_mfma_f32_16x16x32_bf16(pa[kk], vf, o[dt], 0, 0, 0);
            }
        __builtin_amdgcn_s_setprio(0);

        // counted wait: tile kt+1 resident; kt+2's 2 loads stay in flight across barrier
        if (kt + 2 < 16)      asm volatile("s_waitcnt vmcnt(2)" ::: "memory");
        else if (kt + 1 < 16) asm volatile("s_waitcnt vmcnt(0)" ::: "memory");
        __builtin_amdgcn_s_barrier();
    }

    // osum C-layout: row q = lg*4 + r -> exactly the indexing o[dt][r] needs (no shfl)
    float rlr[4];
#pragma unroll
    for (int r = 0; r < 4; ++r) rlr[r] = 1.f / osum[r];
#pragma unroll
    for (int dt = 0; dt < 4; ++dt) {
        int gc = hoff + dt * 16 + l15;
#pragma unroll
        for (int r = 0; r < 4; ++r) {
            int gr = qt * 128 + wid * 16 + lg * 4 + r;
            Om[(rowbase + gr) * 1024 + gc] = f2b(o[dt][r] * rlr[r]);
        }
    }
}

// ---------------- LayerNorm, f32 input -> bf16 output (layer-0 LN1 only) ----------------
__global__ __launch_bounds__(256) void ln_f(
    const float* __restrict__ x, const float* __restrict__ g, const float* __restrict__ bb,
    u16* __restrict__ yb)
{
    const int wid = threadIdx.x >> 6, lane = threadIdx.x & 63;
    const size_t row = (size_t)blockIdx.x * 4 + wid;
    const float* xr = x + row * 1024;
    float4 v[4];
    float s = 0.f, s2 = 0.f;
#pragma unroll
    for (int c = 0; c < 4; ++c) {
        v[c] = *(const float4*)(xr + c * 256 + lane * 4);
        s  += v[c].x + v[c].y + v[c].z + v[c].w;
        s2 += v[c].x * v[c].x + v[c].y * v[c].y + v[c].z * v[c].z + v[c].w * v[c].w;
    }
#pragma unroll
    for (int m = 32; m >= 1; m >>= 1) { s += __shfl_xor(s, m); s2 += __shfl_xor(s2, m); }
    float mean = s * (1.f / 1024.f);
    float var  = s2 * (1.f / 1024.f) - mean * mean;
    float rs = rsqrtf(var + 1e-8f);
#pragma unroll
    for (int c = 0; c < 4; ++c) {
        int col = c * 256 + lane * 4;
        float4 gv = *(const float4*)(g + col);
        float4 bv = *(const float4*)(bb + col);
        ushort4 o4 = make_ushort4(
            f2b((v[c].x - mean) * rs * gv.x + bv.x),
            f2b((v[c].y - mean) * rs * gv.y + bv.y),
            f2b((v[c].z - mean) * rs * gv.z + bv.z),
            f2b((v[c].w - mean) * rs * gv.w + bv.w));
        *(ushort4*)(yb + row * 1024 + col) = o4;
    }
}

// ---------------- LayerNorm, bf16 input -> bf16 output ----------------
__global__ __launch_bounds__(256) void ln_b(
    const u16* __restrict__ x, const float* __restrict__ g, const float* __restrict__ bb,
    u16* __restrict__ yb)
{
    const int wid = threadIdx.x >> 6, lane = threadIdx.x & 63;
    const size_t row = (size_t)blockIdx.x * 4 + wid;
    const u16* xr = x + row * 1024 + lane * 16;
    s8x v0 = *(const s8x*)xr;
    s8x v1 = *(const s8x*)(xr + 8);
    float f[16];
    float s = 0.f, s2 = 0.f;
#pragma unroll
    for (int j = 0; j < 8; ++j) { f[j] = b2f((u16)v0[j]); f[8 + j] = b2f((u16)v1[j]); }
#pragma unroll
    for (int j = 0; j < 16; ++j) { s += f[j]; s2 += f[j] * f[j]; }
#pragma unroll
    for (int m = 32; m >= 1; m >>= 1) { s += __shfl_xor(s, m); s2 += __shfl_xor(s2, m); }
    float mean = s * (1.f / 1024.f);
    float var  = s2 * (1.f / 1024.f) - mean * mean;
    float rs = rsqrtf(var + 1e-8f);
    const int col0 = lane * 16;
    u16 ov[16];
#pragma unroll
    for (int c = 0; c < 4; ++c) {
        float4 gv = *(const float4*)(g + col0 + c * 4);
        float4 bv = *(const float4*)(bb + col0 + c * 4);
        ov[c * 4 + 0] = f2b((f[c * 4 + 0] - mean) * rs * gv.x + bv.x);
        ov[c * 4 + 1] = f2b((f[c * 4 + 1] - mean) * rs * gv.y + bv.y);
        ov[c * 4 + 2] = f2b((f[c * 4 + 2] - mean) * rs * gv.z + bv.z);
        ov[c * 4 + 3] = f2b((f[c * 4 + 3] - mean) * rs * gv.w + bv.w);
    }
    u16* yr = yb + row * 1024 + col0;
    *(ushort4*)(yr + 0)  = make_ushort4(ov[0], ov[1], ov[2], ov[3]);
    *(ushort4*)(yr + 4)  = make_ushort4(ov[4], ov[5], ov[6], ov[7]);
    *(ushort4*)(yr + 8)  = make_ushort4(ov[8], ov[9], ov[10], ov[11]);
    *(ushort4*)(yr + 12) = make_ushort4(ov[12], ov[13], ov[14], ov[15]);
}

// ---------------- f32 -> bf16 convert ----------------
__global__ __launch_bounds__(256) void cvt_kernel(const float* __restrict__ x, u16* __restrict__ y, int n4)
{
    int i = blockIdx.x * 256 + threadIdx.x;
    if (i < n4) {
        float4 v = *(const float4*)(x + (size_t)i * 4);
        ushort4 o = make_ushort4(f2b(v.x), f2b(v.y), f2b(v.z), f2b(v.w));
        *(ushort4*)(y + (size_t)i * 4) = o;
    }
}

// ---------------- transpose-convert: Y[l][i][j] = bf16(X[l][j][i]), 1024x1024/layer ----------------
__global__ __launch_bounds__(256) void cvtT_kernel(const float* __restrict__ X, u16* __restrict__ Y)
{
    __shared__ u16 T[64][65];
    const int l = blockIdx.z;
    const int j0 = blockIdx.y * 64;
    const int i0 = blockIdx.x * 64;
    const float* Xl = X + (size_t)l * 1024 * 1024;
    u16* Yl = Y + (size_t)l * 1024 * 1024;
    const int tr = threadIdx.x >> 4;
    const int tc = threadIdx.x & 15;
#pragma unroll
    for (int k = 0; k < 4; ++k) {
        int j = tr + k * 16;
        float4 v = *(const float4*)(Xl + (size_t)(j0 + j) * 1024 + i0 + tc * 4);
        T[tc * 4 + 0][j] = f2b(v.x);
        T[tc * 4 + 1][j] = f2b(v.y);
        T[tc * 4 + 2][j] = f2b(v.z);
        T[tc * 4 + 3][j] = f2b(v.w);
    }
    __syncthreads();
    const int wr_ = threadIdx.x >> 3;
    const int wc_ = threadIdx.x & 7;
#pragma unroll
    for (int k = 0; k < 2; ++k) {
        int i = wr_ + k * 32;
        u16 tmp[8];
#pragma unroll
        for (int e = 0; e < 8; ++e) tmp[e] = T[i][wc_ * 8 + e];
        *(ushort4*)(Yl + (size_t)(i0 + i) * 1024 + j0 + wc_ * 8)     = make_ushort4(tmp[0], tmp[1], tmp[2], tmp[3]);
        *(ushort4*)(Yl + (size_t)(i0 + i) * 1024 + j0 + wc_ * 8 + 4) = make_ushort4(tmp[4], tmp[5], tmp[6], tmp[7]);
    }
}

// ---------------- bcomb[l][o] = sum_j Wc2[l][o][j]*bc1[l][j] + bc2[l][o] (f32) ----------------
__global__ __launch_bounds__(256) void matvec_kernel(const float* __restrict__ W2, const float* __restrict__ b1,
                                                     const float* __restrict__ b2, float* __restrict__ outv)
{
    const int wid = threadIdx.x >> 6, lane = threadIdx.x & 63;
    int row = blockIdx.x * 4 + wid;
    int l = row >> 10, o = row & 1023;
    const float* wr_ = W2 + (size_t)l * 1024 * 1024 + (size_t)o * 1024;
    const float* b1l = b1 + l * 1024;
    float s = 0.f;
#pragma unroll
    for (int c = 0; c < 4; ++c) {
        float4 w = *(const float4*)(wr_ + c * 256 + lane * 4);
        float4 bv = *(const float4*)(b1l + c * 256 + lane * 4);
        s += w.x * bv.x + w.y * bv.y + w.z * bv.z + w.w * bv.w;
    }
#pragma unroll
    for (int m = 32; m >= 1; m >>= 1) s += __shfl_xor(s, m);
    if (lane == 0) outv[row] = s + b2[l * 1024 + o];
}

// ---------------- mask bitpack + per-row any-flag ----------------
__global__ __launch_bounds__(256) void mask_kernel(const int* __restrict__ am, u32* __restrict__ mw)
{
    size_t idx = (size_t)blockIdx.x * 256 + threadIdx.x;
    unsigned long long bal = __ballot(am[idx] == 0);
    int lane = threadIdx.x & 63;
    if (lane == 0)  mw[idx >> 5] = (u32)bal;
    if (lane == 32) mw[idx >> 5] = (u32)(bal >> 32);
}

__global__ __launch_bounds__(256) void rowflag_kernel(const u32* __restrict__ mw, u32* __restrict__ rf)
{
    int r = blockIdx.x * 256 + threadIdx.x;
    u32 o = 0;
#pragma unroll
    for (int i = 0; i < 32; ++i) o |= mw[r * 32 + i];
    rf[r] = o;
}

// ---------------- host-side orchestration ----------------
extern "C" void kernel_launch(void* const* d_in, const int* in_sizes, int n_in,
                              void* d_out, int out_size, void* d_ws, size_t ws_size,
                              hipStream_t stream)
{
    (void)in_sizes; (void)n_in; (void)out_size; (void)ws_size;

    const float* q_in  = (const float*)d_in[0];
    const float* k_in  = (const float*)d_in[1];
    const float* v_in  = (const float*)d_in[2];
    const int*   amask = (const int*)d_in[3];
    const float* Wqkv  = (const float*)d_in[4];
    const float* bqkv  = (const float*)d_in[5];
    const float* Wo    = (const float*)d_in[6];
    const float* bo    = (const float*)d_in[7];
    const float* ln1g  = (const float*)d_in[8];
    const float* ln1b  = (const float*)d_in[9];
    const float* ln2g  = (const float*)d_in[10];
    const float* ln2b  = (const float*)d_in[11];
    const float* Wc1   = (const float*)d_in[12];
    const float* bc1   = (const float*)d_in[13];
    const float* Wc2   = (const float*)d_in[14];
    const float* bc2   = (const float*)d_in[15];
    const float* lastg = (const float*)d_in[16];
    const float* lastb = (const float*)d_in[17];
    const float* Wfc   = (const float*)d_in[18];
    const float* bfc   = (const float*)d_in[19];
    float* out = (float*)d_out;

    char* base = (char*)d_ws;
    size_t off = 0;
    auto alloc = [&](size_t bytes) -> char* {
        char* p = base + off;
        off = (off + bytes + 255) & ~(size_t)255;
        return p;
    };
    const size_t M1 = 1024 * 1024;          // D*D
    const size_t MT = 8192 * 1024;          // B*S*D
    u16* wqkv_b = (u16*)alloc(6 * M1 * 2);
    u16* wo_b   = (u16*)alloc(2 * M1 * 2);
    u16* wcomb  = (u16*)alloc(2 * M1 * 2);  // (Wc2*Wc1) per layer
    u16* wfc_b  = (u16*)alloc(M1 * 2);
    float* bcomb = (float*)alloc(2 * 1024 * 4);
    float* zb    = (float*)alloc(1024 * 4); // zero bias
    u32* maskw  = (u32*)alloc(8192 * 32 * 4);
    u32* rowfl  = (u32*)alloc(8192 * 4);
    u16* t0 = (u16*)alloc(MT * 2);          // LN1 out / attn out
    u16* t1 = (u16*)alloc(MT * 2);          // post-Wo bf16 state
    u16* qh = (u16*)alloc(MT * 2);
    u16* kh = (u16*)alloc(MT * 2);
    u16* vt = (u16*)alloc(MT * 2);          // V^T: [1024 d_global][8192 s_global]
    u16* xb = (u16*)alloc(MT * 2);          // LN2 out (k1) / layer-0 v_in cvt
    u16* x2 = (u16*)alloc(MT * 2);          // k-state bf16 / layer-0 k_in cvt
    // prep-phase scratch aliases (consumed before qh/kh are first written):
    u16* wc1t  = qh;                        // Wc1^T bf16, 2*M1
    u16* wc2_b = kh;                        // Wc2 bf16, 2*M1

    // ---- weight prep ----
    cvt_kernel<<<6 * M1 / 1024, 256, 0, stream>>>(Wqkv, wqkv_b, (int)(6 * M1 / 4));
    cvt_kernel<<<2 * M1 / 1024, 256, 0, stream>>>(Wo,   wo_b,   (int)(2 * M1 / 4));
    cvt_kernel<<<M1 / 1024, 256, 0, stream>>>(Wfc, wfc_b, (int)(M1 / 4));
    cvt_kernel<<<2 * M1 / 1024, 256, 0, stream>>>(Wc2, wc2_b, (int)(2 * M1 / 4));
    cvtT_kernel<<<dim3(16, 16, 2), 256, 0, stream>>>(Wc1, wc1t);
    hipMemsetAsync(zb, 0, 1024 * 4, stream);
    gemm_z2<<<dim3(8, 8, 2), 256, 0, stream>>>(
        wc2_b, wc1t, zb, wcomb, 1.f,
        wc2_b + M1, wc1t + M1, zb, wcomb + M1, 1.f);
    matvec_kernel<<<512, 256, 0, stream>>>(Wc2, bc1, bc2, bcomb);
    mask_kernel<<<32768, 256, 0, stream>>>(amask, maskw);
    rowflag_kernel<<<32, 256, 0, stream>>>(maskw, rowfl);

    dim3 g8(8192 / 256, 1024 / 128);    // (32, 8) standard
    dim3 v8(1024 / 256, 8192 / 128);    // (4, 64) swapped V-projection
    dim3 gqk(8192 / 256, 1024 / 256, 2); // (32, 4, 2) paired Q+K 256^2
    const float QS = 0.125f * 1.44269504f;   // (1/sqrt(dk)) * log2(e): exp2-domain scores
    const int D = 1024;
    for (int i = 0; i < 2; ++i) {
        // LN1 -> t0 (bf16)
        if (i == 0) {
            ln_f<<<2048, 256, 0, stream>>>(q_in, ln1g, ln1b, t0);
            cvt_kernel<<<8192, 256, 0, stream>>>(k_in, x2, (int)(MT / 4));
            cvt_kernel<<<8192, 256, 0, stream>>>(v_in, xb, (int)(MT / 4));
        } else {
            ln_b<<<2048, 256, 0, stream>>>(x2, ln1g + i * D, ln1b + i * D, t0);
        }
        // Q (prescaled into exp2 domain) and K projections, paired 256^2 kernel
        gemm_qk256<<<gqk, 512, 0, stream>>>(
            t0, wqkv_b + (size_t)(i * 3 + 0) * M1, bqkv + (i * 3 + 0) * D, qh, QS,
            x2, wqkv_b + (size_t)(i * 3 + 1) * M1, bqkv + (i * 3 + 1) * D, kh, 1.f);
        // V projection, swapped: vt[d][s] = W_v · X^T  (row-bias)
        const u16* vin_b = (i == 0) ? xb : x2;
        gemm8<8 | 16, 8192><<<v8, 512, 0, stream>>>(wqkv_b + (size_t)(i * 3 + 2) * M1, vin_b,
                                                    bqkv + (i * 3 + 2) * D, nullptr, nullptr, vt, 1.f);
        // attention -> t0
        attn_kernel<<<dim3(128, 8), 512, 0, stream>>>(qh, kh, vt, maskw, rowfl, t0);
        // t1 = f2b(k_state + relu(attn @ Wo^T + bo))   (bf16 residual)
        gemm8<1 | 2 | 8, 1024><<<g8, 512, 0, stream>>>(t0, wo_b + (size_t)i * M1,
                                                       bo + i * D, x2, nullptr, t1, 1.f);
        // k1 = LN2(t1) -> xb (bf16)
        ln_b<<<2048, 256, 0, stream>>>(t1, ln2g + i * D, ln2b + i * D, xb);
        // folded FFN: x2 = f2b(k1 + k1 @ Wcomb^T + bcomb)   (res = xb itself)
        gemm8<2 | 8, 1024><<<g8, 512, 0, stream>>>(xb, wcomb + (size_t)i * M1,
                                                   bcomb + i * 1024, xb, nullptr, x2, 1.f);
    }
    // final LN + FC
    ln_b<<<2048, 256, 0, stream>>>(x2, lastg, lastb, t0);
    gemm8<4, 1024><<<g8, 512, 0, stream>>>(t0, wfc_b, bfc, nullptr, out, nullptr, 1.f);
}

// Round 15
// 478.004 us; speedup vs baseline: 1.0371x; 1.0371x over previous
//
#include <hip/hip_runtime.h>

typedef __attribute__((ext_vector_type(8))) short s8x;   // 8 x bf16 (raw bits)
typedef __attribute__((ext_vector_type(4))) float f4x;
typedef unsigned short u16;
typedef unsigned int u32;

#define DEV static __device__ __forceinline__

DEV u16 f2b(float f) {
    union { float f; u32 u; } v; v.f = f;
    u32 r = v.u + 0x7FFFu + ((v.u >> 16) & 1u);
    return (u16)(r >> 16);
}

DEV float b2f(u16 x) {
    union { u32 u; float f; } v; v.u = (u32)x << 16;
    return v.f;
}

DEV u32 pk2(float lo, float hi) {   // v_cvt_pk_bf16_f32: low16=lo, high16=hi
    u32 r;
    asm("v_cvt_pk_bf16_f32 %0, %1, %2" : "=v"(r) : "v"(lo), "v"(hi));
    return r;
}

DEV float exp2_raw(float x) {       // D = 2^x (v_exp_f32 native semantics)
    float r;
    asm("v_exp_f32 %0, %1" : "=v"(r) : "v"(x));
    return r;
}

DEV void gload16(const void* g, void* lds) {
    __builtin_amdgcn_global_load_lds(
        (const __attribute__((address_space(1))) void*)g,
        (__attribute__((address_space(3))) void*)lds, 16, 0, 0);
}

#define GK 1024
#define BM 128
#define BN 128
#define BK 64

// ---------------- 8-phase GEMM core pieces (T2 swizzle, T3/T4 counted vmcnt, T5 setprio) ----
// Swizzle (both-sides, rule #21): LDS[row][cd] = G[row][cd ^ (row&7)]; read chunk = want ^ (row&7).

DEV void stage_unit(const u16* __restrict__ g, char* l, int tid) {
    // one 16KB unit = 128 rows x 128B; 512 threads x 2 x 16B
#pragma unroll
    for (int i = 0; i < 2; ++i) {
        int db = i * 8192 + tid * 16;
        int row = db >> 7;
        int cs = ((db >> 4) & 7) ^ (row & 7);
        gload16(g + (size_t)row * 1024 + cs * 8, l + db);
    }
}

DEV s8x lds_frag(const char* Lbase, int row, int kk, int lg) {
    int cb = (kk * 64 + lg * 16) ^ ((row & 7) << 4);
    return *(const s8x*)(Lbase + row * 128 + cb);
}

// ---------------- gemm8: C[M,N] = A[M,K] @ W[N,K]^T, 256x128 tile, 8 waves ----------------
// FLAGS: 1=RELU, 2=RES (bf16 residual add after relu), 4=WF (f32 out), 8=WB (bf16 out), 16=row-bias
template<int FLAGS, int NN>
__global__ __launch_bounds__(512, 2) void gemm8(
    const u16* __restrict__ A, const u16* __restrict__ W,
    const float* __restrict__ bias, const u16* __restrict__ res,
    float* __restrict__ outf, u16* __restrict__ outb, float scl)
{
    constexpr bool RELU = (FLAGS & 1) != 0;
    constexpr bool RES  = (FLAGS & 2) != 0;
    constexpr bool WF   = (FLAGS & 4) != 0;
    constexpr bool WB   = (FLAGS & 8) != 0;
    constexpr bool RBIA = (FLAGS & 16) != 0;

    __shared__ __attribute__((aligned(16))) u16 As[3][256 * 64];   // 96 KB
    __shared__ __attribute__((aligned(16))) u16 Bs[3][128 * 64];   // 48 KB

    const int tid = threadIdx.x, lane = tid & 63, wid = tid >> 6;
    const int l15 = lane & 15, lg = lane >> 4;
    const int wm = wid >> 1, wn = wid & 1;
    const int bm = blockIdx.x, bn = blockIdx.y;

    const u16* Ab = A + (size_t)bm * 256 * GK;
    const u16* Wb = W + (size_t)bn * 128 * GK;

    f4x acc[4][4];
#pragma unroll
    for (int i = 0; i < 4; ++i)
#pragma unroll
        for (int j = 0; j < 4; ++j) { f4x z = {0.f, 0.f, 0.f, 0.f}; acc[i][j] = z; }

    char* a0 = (char*)As[0]; char* a1 = (char*)As[1]; char* a2 = (char*)As[2];
    char* b0 = (char*)Bs[0]; char* b1 = (char*)Bs[1]; char* b2 = (char*)Bs[2];

    stage_unit(Ab + 0 * 64,                 a0,        tid);
    stage_unit(Ab + 128 * GK + 0 * 64,      a0 + 16384, tid);
    stage_unit(Wb + 0 * 64,                 b0,        tid);
    stage_unit(Ab + 1 * 64,                 a1,        tid);
    stage_unit(Ab + 128 * GK + 1 * 64,      a1 + 16384, tid);
    stage_unit(Wb + 1 * 64,                 b1,        tid);
    asm volatile("s_waitcnt vmcnt(6)" ::: "memory");
    __builtin_amdgcn_s_barrier();

    for (int t = 0; t < 16; ++t) {
        const bool st = (t < 14);
        s8x bfr[4][2], afr[2][2];
#pragma unroll
        for (int ni = 0; ni < 4; ++ni)
#pragma unroll
            for (int kk = 0; kk < 2; ++kk)
                bfr[ni][kk] = lds_frag(b0, wn * 64 + ni * 16 + l15, kk, lg);
#pragma unroll
        for (int mi = 0; mi < 2; ++mi)
#pragma unroll
            for (int kk = 0; kk < 2; ++kk)
                afr[mi][kk] = lds_frag(a0, wm * 64 + mi * 16 + l15, kk, lg);
        if (st) {
            stage_unit(Ab + (t + 2) * 64,            a2,         tid);
            stage_unit(Ab + 128 * GK + (t + 2) * 64, a2 + 16384, tid);
        }
        __builtin_amdgcn_s_barrier();
        asm volatile("s_waitcnt lgkmcnt(0)" ::: "memory");
        __builtin_amdgcn_sched_barrier(0);
        __builtin_amdgcn_s_setprio(1);
#pragma unroll
        for (int kk = 0; kk < 2; ++kk)
#pragma unroll
            for (int mi = 0; mi < 2; ++mi)
#pragma unroll
                for (int ni = 0; ni < 4; ++ni)
                    acc[mi][ni] = __builtin_amdgcn_mfma_f32_16x16x32_bf16(afr[mi][kk], bfr[ni][kk], acc[mi][ni], 0, 0, 0);
        __builtin_amdgcn_s_setprio(0);
        __builtin_amdgcn_s_barrier();

        s8x afr2[2][2];
#pragma unroll
        for (int mi = 0; mi < 2; ++mi)
#pragma unroll
            for (int kk = 0; kk < 2; ++kk)
                afr2[mi][kk] = lds_frag(a0, wm * 64 + (mi + 2) * 16 + l15, kk, lg);
        if (st) stage_unit(Wb + (t + 2) * 64, b2, tid);
        __builtin_amdgcn_s_barrier();
        asm volatile("s_waitcnt lgkmcnt(0)" ::: "memory");
        __builtin_amdgcn_sched_barrier(0);
        __builtin_amdgcn_s_setprio(1);
#pragma unroll
        for (int kk = 0; kk < 2; ++kk)
#pragma unroll
            for (int mi = 0; mi < 2; ++mi)
#pragma unroll
                for (int ni = 0; ni < 4; ++ni)
                    acc[mi + 2][ni] = __builtin_amdgcn_mfma_f32_16x16x32_bf16(afr2[mi][kk], bfr[ni][kk], acc[mi + 2][ni], 0, 0, 0);
        __builtin_amdgcn_s_setprio(0);
        if (st) asm volatile("s_waitcnt vmcnt(6)" ::: "memory");
        else    asm volatile("s_waitcnt vmcnt(0)" ::: "memory");
        __builtin_amdgcn_s_barrier();

        char* tA = a0; a0 = a1; a1 = a2; a2 = tA;
        char* tB = b0; b0 = b1; b1 = b2; b2 = tB;
    }

#pragma unroll
    for (int ni = 0; ni < 4; ++ni) {
        int gcol = bn * 128 + wn * 64 + ni * 16 + l15;
        float bvc = RBIA ? 0.f : bias[gcol];
#pragma unroll
        for (int mi = 0; mi < 4; ++mi) {
            int grow0 = bm * 256 + wm * 64 + mi * 16 + lg * 4;
#pragma unroll
            for (int r = 0; r < 4; ++r) {
                float bv = RBIA ? bias[grow0 + r] : bvc;
                float v = (acc[mi][ni][r] + bv) * scl;
                if (RELU) v = fmaxf(v, 0.f);
                size_t oidx = (size_t)(grow0 + r) * NN + gcol;
                if (RES) v += b2f(res[oidx]);
                if (WF) outf[oidx] = v;
                if (WB) outb[oidx] = f2b(v);
            }
        }
    }
}

// ---------------- gemm_qk256: z=2-paired 256x256-tile GEMM (Q and K projections) ----------------
__global__ __launch_bounds__(512, 2) void gemm_qk256(
    const u16* __restrict__ A0p, const u16* __restrict__ W0p, const float* __restrict__ b0p,
    u16* __restrict__ o0p, float s0,
    const u16* __restrict__ A1p, const u16* __restrict__ W1p, const float* __restrict__ b1p,
    u16* __restrict__ o1p, float s1)
{
    const int z = blockIdx.z;
    const u16* A = z ? A1p : A0p;
    const u16* W = z ? W1p : W0p;
    const float* bias = z ? b1p : b0p;
    u16* outb = z ? o1p : o0p;
    const float scl = z ? s1 : s0;

    __shared__ __attribute__((aligned(16))) u16 As[3][256 * 64];   // 96 KB
    __shared__ __attribute__((aligned(16))) u16 Bs[2][256 * 64];   // 64 KB

    const int tid = threadIdx.x, lane = tid & 63, wid = tid >> 6;
    const int l15 = lane & 15, lg = lane >> 4;
    const int wm = wid >> 2;
    const int wn = wid & 3;
    const int bm = blockIdx.x, bn = blockIdx.y;

    const u16* Ab = A + (size_t)bm * 256 * GK;
    const u16* Wb = W + (size_t)bn * 256 * GK;

    f4x acc[8][4];
#pragma unroll
    for (int i = 0; i < 8; ++i)
#pragma unroll
        for (int j = 0; j < 4; ++j) { f4x zz = {0.f, 0.f, 0.f, 0.f}; acc[i][j] = zz; }

    char* a0 = (char*)As[0]; char* a1 = (char*)As[1]; char* a2 = (char*)As[2];
    char* b0 = (char*)Bs[0]; char* b1 = (char*)Bs[1];

    stage_unit(Ab + 0 * 64,            a0,         tid);
    stage_unit(Ab + 128 * GK + 0 * 64, a0 + 16384, tid);
    stage_unit(Wb + 0 * 64,            b0,         tid);
    stage_unit(Wb + 128 * GK + 0 * 64, b0 + 16384, tid);
    stage_unit(Ab + 1 * 64,            a1,         tid);
    stage_unit(Ab + 128 * GK + 1 * 64, a1 + 16384, tid);
    asm volatile("s_waitcnt vmcnt(4)" ::: "memory");
    __builtin_amdgcn_s_barrier();

    const char* aW = nullptr;
    const char* bW = nullptr;
    for (int t = 0; t < 16; ++t) {
        aW = a0 + wm * 16384;
        bW = b0 + (wn >> 1) * 16384;
        const int brow0 = (wn & 1) * 64;

        s8x bfr[4][2], afr[4][2];
#pragma unroll
        for (int ni = 0; ni < 4; ++ni)
#pragma unroll
            for (int kk = 0; kk < 2; ++kk)
                bfr[ni][kk] = lds_frag(bW, brow0 + ni * 16 + l15, kk, lg);
#pragma unroll
        for (int mi = 0; mi < 4; ++mi)
#pragma unroll
            for (int kk = 0; kk < 2; ++kk)
                afr[mi][kk] = lds_frag(aW, mi * 16 + l15, kk, lg);
        if (t + 1 < 16) {
            stage_unit(Wb + (t + 1) * 64,            b1,         tid);
            stage_unit(Wb + 128 * GK + (t + 1) * 64, b1 + 16384, tid);
        }
        __builtin_amdgcn_s_barrier();
        asm volatile("s_waitcnt lgkmcnt(0)" ::: "memory");
        __builtin_amdgcn_sched_barrier(0);
        __builtin_amdgcn_s_setprio(1);
#pragma unroll
        for (int kk = 0; kk < 2; ++kk)
#pragma unroll
            for (int mi = 0; mi < 4; ++mi)
#pragma unroll
                for (int ni = 0; ni < 4; ++ni)
                    acc[mi][ni] = __builtin_amdgcn_mfma_f32_16x16x32_bf16(afr[mi][kk], bfr[ni][kk], acc[mi][ni], 0, 0, 0);
        __builtin_amdgcn_s_setprio(0);
        __builtin_amdgcn_s_barrier();

        s8x afr2[4][2];
#pragma unroll
        for (int mi = 0; mi < 4; ++mi)
#pragma unroll
            for (int kk = 0; kk < 2; ++kk)
                afr2[mi][kk] = lds_frag(aW, (mi + 4) * 16 + l15, kk, lg);
        if (t + 2 < 16) {
            stage_unit(Ab + (t + 2) * 64,            a2,         tid);
            stage_unit(Ab + 128 * GK + (t + 2) * 64, a2 + 16384, tid);
        }
        __builtin_amdgcn_s_barrier();
        asm volatile("s_waitcnt lgkmcnt(0)" ::: "memory");
        __builtin_amdgcn_sched_barrier(0);
        __builtin_amdgcn_s_setprio(1);
#pragma unroll
        for (int kk = 0; kk < 2; ++kk)
#pragma unroll
            for (int mi = 0; mi < 4; ++mi)
#pragma unroll
                for (int ni = 0; ni < 4; ++ni)
                    acc[mi + 4][ni] = __builtin_amdgcn_mfma_f32_16x16x32_bf16(afr2[mi][kk], bfr[ni][kk], acc[mi + 4][ni], 0, 0, 0);
        __builtin_amdgcn_s_setprio(0);

        if (t <= 13)      asm volatile("s_waitcnt vmcnt(4)" ::: "memory");
        else if (t == 14) asm volatile("s_waitcnt vmcnt(0)" ::: "memory");
        __builtin_amdgcn_s_barrier();

        char* tA = a0; a0 = a1; a1 = a2; a2 = tA;
        char* tB = b0; b0 = b1; b1 = tB;
    }

#pragma unroll
    for (int ni = 0; ni < 4; ++ni) {
        int gcol = bn * 256 + wn * 64 + ni * 16 + l15;
        float bvc = bias[gcol];
#pragma unroll
        for (int mi = 0; mi < 8; ++mi) {
            int grow0 = bm * 256 + wm * 128 + mi * 16 + lg * 4;
#pragma unroll
            for (int r = 0; r < 4; ++r) {
                float v = (acc[mi][ni][r] + bvc) * scl;
                outb[(size_t)(grow0 + r) * 1024 + gcol] = f2b(v);
            }
        }
    }
}

// ---- z-batched 2-phase variant (weight-prep only): out = f2b((acc + bias) * scl) ----
__global__ __launch_bounds__(256) void gemm_z2(
    const u16* __restrict__ A0, const u16* __restrict__ W0, const float* __restrict__ b0,
    u16* __restrict__ o0, float s0,
    const u16* __restrict__ A1, const u16* __restrict__ W1, const float* __restrict__ b1,
    u16* __restrict__ o1, float s1)
{
    const int z = blockIdx.z;
    const u16* A = z ? A1 : A0;
    const u16* W = z ? W1 : W0;
    const float* bias = z ? b1 : b0;
    u16* outb = z ? o1 : o0;
    const float scl = z ? s1 : s0;

    __shared__ __attribute__((aligned(16))) u16 As[2][BM * BK];
    __shared__ __attribute__((aligned(16))) u16 Bs[2][BN * BK];

    const int tid  = threadIdx.x;
    const int lane = tid & 63;
    const int wid  = tid >> 6;
    const int wr = wid >> 1, wc = wid & 1;
    const int bm = blockIdx.x, bn = blockIdx.y;
    const int l15 = lane & 15;
    const int lg  = lane >> 4;

    const u16* Ab = A + (size_t)bm * BM * GK;
    const u16* Wb = W + (size_t)bn * BN * GK;

    const int prow = tid >> 3;
    const int pcol = (tid & 7) * 8;

    f4x acc[4][4];
#pragma unroll
    for (int i = 0; i < 4; ++i)
#pragma unroll
        for (int j = 0; j < 4; ++j) { f4x z_ = {0.f, 0.f, 0.f, 0.f}; acc[i][j] = z_; }

#pragma unroll
    for (int c = 0; c < 4; ++c) {
        int row = c * 32 + prow;
        gload16(Ab + (size_t)row * GK + pcol, &As[0][row * BK + pcol]);
    }
#pragma unroll
    for (int c = 0; c < 4; ++c) {
        int row = c * 32 + prow;
        gload16(Wb + (size_t)row * GK + pcol, &Bs[0][row * BK + pcol]);
    }

    const int nkt = GK / BK;
    int cur = 0;
    for (int kt = 0; kt < nkt; ++kt) {
        __syncthreads();
        if (kt + 1 < nkt) {
            const u16* Ak = Ab + (kt + 1) * BK;
            const u16* Wk = Wb + (kt + 1) * BK;
#pragma unroll
            for (int c = 0; c < 4; ++c) {
                int row = c * 32 + prow;
                gload16(Ak + (size_t)row * GK + pcol, &As[cur ^ 1][row * BK + pcol]);
            }
#pragma unroll
            for (int c = 0; c < 4; ++c) {
                int row = c * 32 + prow;
                gload16(Wk + (size_t)row * GK + pcol, &Bs[cur ^ 1][row * BK + pcol]);
            }
        }
        const u16* Ac = As[cur];
        const u16* Bc = Bs[cur];
#pragma unroll
        for (int kk = 0; kk < 2; ++kk) {
            s8x a[4], b[4];
#pragma unroll
            for (int mi = 0; mi < 4; ++mi)
                a[mi] = *(const s8x*)(Ac + (wr * 64 + mi * 16 + l15) * BK + kk * 32 + lg * 8);
#pragma unroll
            for (int ni = 0; ni < 4; ++ni)
                b[ni] = *(const s8x*)(Bc + (wc * 64 + ni * 16 + l15) * BK + kk * 32 + lg * 8);
#pragma unroll
            for (int mi = 0; mi < 4; ++mi)
#pragma unroll
                for (int ni = 0; ni < 4; ++ni)
                    acc[mi][ni] = __builtin_amdgcn_mfma_f32_16x16x32_bf16(a[mi], b[ni], acc[mi][ni], 0, 0, 0);
        }
        cur ^= 1;
    }

#pragma unroll
    for (int ni = 0; ni < 4; ++ni) {
        int gcol = bn * BN + wc * 64 + ni * 16 + l15;
        float bvc = bias[gcol];
#pragma unroll
        for (int mi = 0; mi < 4; ++mi) {
            int grow0 = bm * BM + wr * 64 + mi * 16 + lg * 4;
#pragma unroll
            for (int r = 0; r < 4; ++r) {
                float v = (acc[mi][ni][r] + bvc) * scl;
                outb[(size_t)(grow0 + r) * 1024 + gcol] = f2b(v);
            }
        }
    }
}

// ---------------- Attention v9 (round-13 best): 3-deep counted pipeline, no-clip exp2, ----
// MFMA row-sum via ones B-frag, Ps LDS round-trip, full unroll.
__global__ __launch_bounds__(512) void attn_kernel(
    const u16* __restrict__ Qm, const u16* __restrict__ Km, const u16* __restrict__ Vt,
    const u32* __restrict__ maskw, const u32* __restrict__ rowfl,
    u16* __restrict__ Om)
{
    const int bh = blockIdx.x;
    const int b  = bh >> 4;
    const int h  = bh & 15;
    const int qt = blockIdx.y;
    const int tid = threadIdx.x, lane = tid & 63, wid = tid >> 6;
    const int l15 = lane & 15, lg = lane >> 4;

    __shared__ __attribute__((aligned(16))) u16 Ks[3][64 * 64];   // 24 KB
    __shared__ __attribute__((aligned(16))) u16 Vs[3][64 * 64];   // 24 KB
    __shared__ __attribute__((aligned(16))) u16 Ps[8][16][64];    // 16 KB
    __shared__ int anymask;

    const size_t rowbase = (size_t)b * 1024;
    const int hoff = h * 64;

    if (tid == 0) anymask = 0;

    const int so   = tid * 16;
    const int srow = so >> 7;
    const int sch  = ((so >> 4) & 7) ^ (srow & 7);
    const int vswz = (l15 & 7) << 4;

    const u16* Kbase = Km + rowbase * 1024 + hoff + (size_t)srow * 1024 + sch * 8;
    const u16* Vbase = Vt + (size_t)(hoff + srow) * 8192 + b * 1024 + sch * 8;

    // prologue: stage tiles 0 and 1
    gload16(Kbase + 0 * 64 * 1024, (char*)Ks[0] + so);
    gload16(Vbase + 0 * 64,        (char*)Vs[0] + so);
    gload16(Kbase + 1 * 64 * 1024, (char*)Ks[1] + so);
    gload16(Vbase + 1 * 64,        (char*)Vs[1] + so);

    const int qrow = qt * 128 + wid * 16 + l15;
    s8x qf[2];
#pragma unroll
    for (int kk = 0; kk < 2; ++kk)
        qf[kk] = *(const s8x*)(Qm + (rowbase + qrow) * 1024 + hoff + kk * 32 + lg * 8);

    __syncthreads();   // anymask = 0 visible
    if (tid < 128) {
        if (rowfl[rowbase + qt * 128 + tid]) atomicOr(&anymask, 1);
    }

    f4x o[4];
#pragma unroll
    for (int d = 0; d < 4; ++d) { f4x z = {0.f, 0.f, 0.f, 0.f}; o[d] = z; }
    f4x osum = {0.f, 0.f, 0.f, 0.f};
    const s8x ones = {(short)0x3F80, (short)0x3F80, (short)0x3F80, (short)0x3F80,
                      (short)0x3F80, (short)0x3F80, (short)0x3F80, (short)0x3F80};

    asm volatile("s_waitcnt vmcnt(0)" ::: "memory");   // tiles 0,1 + qf + rowfl done
    __syncthreads();                                    // staging + atomicOr visible
    const int am = anymask;

#pragma unroll
    for (int kt = 0; kt < 16; ++kt) {
        const char* kc = (const char*)Ks[kt % 3];
        const char* vc = (const char*)Vs[kt % 3];
        // T14/T3: issue tile kt+2 staging into the buffer freed at kt-1's barrier
        if (kt + 2 < 16) {
            gload16(Kbase + (size_t)(kt + 2) * 64 * 1024, (char*)Ks[(kt + 2) % 3] + so);
            gload16(Vbase + (kt + 2) * 64,                (char*)Vs[(kt + 2) % 3] + so);
        }

        // swapped QK^T: C[k][q]; scores in log2 units (Q prescaled by log2e/8)
        f4x sc[4];
#pragma unroll
        for (int ni = 0; ni < 4; ++ni) { f4x z = {0.f, 0.f, 0.f, 0.f}; sc[ni] = z; }
        __builtin_amdgcn_s_setprio(1);
#pragma unroll
        for (int kk = 0; kk < 2; ++kk) {
#pragma unroll
            for (int ni = 0; ni < 4; ++ni) {
                int row = ni * 16 + l15;
                int cb  = (kk * 64 + lg * 16) ^ ((row & 7) << 4);
                s8x kf = *(const s8x*)(kc + row * 128 + cb);
                sc[ni] = __builtin_amdgcn_mfma_f32_16x16x32_bf16(kf, qf[kk], sc[ni], 0, 0, 0);
            }
        }
        __builtin_amdgcn_s_setprio(0);

        if (am) {
            int qg = qt * 128 + wid * 16 + l15;
#pragma unroll
            for (int ni = 0; ni < 4; ++ni)
#pragma unroll
                for (int r = 0; r < 4; ++r) {
                    int kcol = kt * 64 + ni * 16 + lg * 4 + r;
                    u32 wb_ = maskw[(rowbase + qg) * 32 + (kcol >> 5)];
                    if (wb_ & (1u << (kcol & 31))) sc[ni][r] = -1e9f;
                }
        }

        // p = 2^s raw (no clip; masked -1e9 underflows to 0)
#pragma unroll
        for (int ni = 0; ni < 4; ++ni)
#pragma unroll
            for (int r = 0; r < 4; ++r)
                sc[ni][r] = exp2_raw(sc[ni][r]);

        // pack P (bf16) -> per-wave swizzled LDS, read back as A-frag
#pragma unroll
        for (int ni = 0; ni < 4; ++ni) {
            uint2 w; w.x = pk2(sc[ni][0], sc[ni][1]); w.y = pk2(sc[ni][2], sc[ni][3]);
            *(uint2*)((char*)&Ps[wid][l15][0] + ((ni * 32 + lg * 8) ^ vswz)) = w;
        }
        s8x pa[2];
#pragma unroll
        for (int kk = 0; kk < 2; ++kk)
            pa[kk] = *(const s8x*)((const char*)&Ps[wid][l15][0] + ((kk * 64 + lg * 16) ^ vswz));

        __builtin_amdgcn_s_setprio(1);
        // denominator on the matrix pipe: osum[q] += sum_k P[q][k]
#pragma unroll
        for (int kk = 0; kk < 2; ++kk)
            osum = __builtin_amdgcn_mfma_f32_16x16x32_bf16(pa[kk], ones, osum, 0, 0, 0);
#pragma unroll
        for (int dt = 0; dt < 4; ++dt)
#pragma unroll
            for (int kk = 0; kk < 2; ++kk) {
                int row = dt * 16 + l15;
                int cb  = (kk * 64 + lg * 16) ^ ((row & 7) << 4);
                s8x vf = *(const s8x*)(vc + row * 128 + cb);
                o[dt] = __builtin_amdgcn_mfma_f32_16x16x32_bf16(pa[kk], vf, o[dt], 0, 0, 0);
            }
        __builtin_amdgcn_s_setprio(0);

        // counted wait: tile kt+1 resident; kt+2's 2 loads stay in flight across barrier
        if (kt + 2 < 16)      asm volatile("s_waitcnt vmcnt(2)" ::: "memory");
        else if (kt + 1 < 16) asm volatile("s_waitcnt vmcnt(0)" ::: "memory");
        __builtin_amdgcn_s_barrier();
    }

    // osum C-layout: row q = lg*4 + r -> exactly the indexing o[dt][r] needs (no shfl)
    float rlr[4];
#pragma unroll
    for (int r = 0; r < 4; ++r) rlr[r] = 1.f / osum[r];
#pragma unroll
    for (int dt = 0; dt < 4; ++dt) {
        int gc = hoff + dt * 16 + l15;
#pragma unroll
        for (int r = 0; r < 4; ++r) {
            int gr = qt * 128 + wid * 16 + lg * 4 + r;
            Om[(rowbase + gr) * 1024 + gc] = f2b(o[dt][r] * rlr[r]);
        }
    }
}

// ---------------- LayerNorm, f32 input -> bf16 output (layer-0 LN1 only) ----------------
__global__ __launch_bounds__(256) void ln_f(
    const float* __restrict__ x, const float* __restrict__ g, const float* __restrict__ bb,
    u16* __restrict__ yb)
{
    const int wid = threadIdx.x >> 6, lane = threadIdx.x & 63;
    const size_t row = (size_t)blockIdx.x * 4 + wid;
    const float* xr = x + row * 1024;
    float4 v[4];
    float s = 0.f, s2 = 0.f;
#pragma unroll
    for (int c = 0; c < 4; ++c) {
        v[c] = *(const float4*)(xr + c * 256 + lane * 4);
        s  += v[c].x + v[c].y + v[c].z + v[c].w;
        s2 += v[c].x * v[c].x + v[c].y * v[c].y + v[c].z * v[c].z + v[c].w * v[c].w;
    }
#pragma unroll
    for (int m = 32; m >= 1; m >>= 1) { s += __shfl_xor(s, m); s2 += __shfl_xor(s2, m); }
    float mean = s * (1.f / 1024.f);
    float var  = s2 * (1.f / 1024.f) - mean * mean;
    float rs = rsqrtf(var + 1e-8f);
#pragma unroll
    for (int c = 0; c < 4; ++c) {
        int col = c * 256 + lane * 4;
        float4 gv = *(const float4*)(g + col);
        float4 bv = *(const float4*)(bb + col);
        ushort4 o4 = make_ushort4(
            f2b((v[c].x - mean) * rs * gv.x + bv.x),
            f2b((v[c].y - mean) * rs * gv.y + bv.y),
            f2b((v[c].z - mean) * rs * gv.z + bv.z),
            f2b((v[c].w - mean) * rs * gv.w + bv.w));
        *(ushort4*)(yb + row * 1024 + col) = o4;
    }
}

// ---------------- LayerNorm, bf16 input -> bf16 output ----------------
__global__ __launch_bounds__(256) void ln_b(
    const u16* __restrict__ x, const float* __restrict__ g, const float* __restrict__ bb,
    u16* __restrict__ yb)
{
    const int wid = threadIdx.x >> 6, lane = threadIdx.x & 63;
    const size_t row = (size_t)blockIdx.x * 4 + wid;
    const u16* xr = x + row * 1024 + lane * 16;
    s8x v0 = *(const s8x*)xr;
    s8x v1 = *(const s8x*)(xr + 8);
    float f[16];
    float s = 0.f, s2 = 0.f;
#pragma unroll
    for (int j = 0; j < 8; ++j) { f[j] = b2f((u16)v0[j]); f[8 + j] = b2f((u16)v1[j]); }
#pragma unroll
    for (int j = 0; j < 16; ++j) { s += f[j]; s2 += f[j] * f[j]; }
#pragma unroll
    for (int m = 32; m >= 1; m >>= 1) { s += __shfl_xor(s, m); s2 += __shfl_xor(s2, m); }
    float mean = s * (1.f / 1024.f);
    float var  = s2 * (1.f / 1024.f) - mean * mean;
    float rs = rsqrtf(var + 1e-8f);
    const int col0 = lane * 16;
    u16 ov[16];
#pragma unroll
    for (int c = 0; c < 4; ++c) {
        float4 gv = *(const float4*)(g + col0 + c * 4);
        float4 bv = *(const float4*)(bb + col0 + c * 4);
        ov[c * 4 + 0] = f2b((f[c * 4 + 0] - mean) * rs * gv.x + bv.x);
        ov[c * 4 + 1] = f2b((f[c * 4 + 1] - mean) * rs * gv.y + bv.y);
        ov[c * 4 + 2] = f2b((f[c * 4 + 2] - mean) * rs * gv.z + bv.z);
        ov[c * 4 + 3] = f2b((f[c * 4 + 3] - mean) * rs * gv.w + bv.w);
    }
    u16* yr = yb + row * 1024 + col0;
    *(ushort4*)(yr + 0)  = make_ushort4(ov[0], ov[1], ov[2], ov[3]);
    *(ushort4*)(yr + 4)  = make_ushort4(ov[4], ov[5], ov[6], ov[7]);
    *(ushort4*)(yr + 8)  = make_ushort4(ov[8], ov[9], ov[10], ov[11]);
    *(ushort4*)(yr + 12) = make_ushort4(ov[12], ov[13], ov[14], ov[15]);
}

// ---------------- f32 -> bf16 convert ----------------
__global__ __launch_bounds__(256) void cvt_kernel(const float* __restrict__ x, u16* __restrict__ y, int n4)
{
    int i = blockIdx.x * 256 + threadIdx.x;
    if (i < n4) {
        float4 v = *(const float4*)(x + (size_t)i * 4);
        ushort4 o = make_ushort4(f2b(v.x), f2b(v.y), f2b(v.z), f2b(v.w));
        *(ushort4*)(y + (size_t)i * 4) = o;
    }
}

// ---------------- transpose-convert: Y[l][i][j] = bf16(X[l][j][i]), 1024x1024/layer ----------------
__global__ __launch_bounds__(256) void cvtT_kernel(const float* __restrict__ X, u16* __restrict__ Y)
{
    __shared__ u16 T[64][65];
    const int l = blockIdx.z;
    const int j0 = blockIdx.y * 64;
    const int i0 = blockIdx.x * 64;
    const float* Xl = X + (size_t)l * 1024 * 1024;
    u16* Yl = Y + (size_t)l * 1024 * 1024;
    const int tr = threadIdx.x >> 4;
    const int tc = threadIdx.x & 15;
#pragma unroll
    for (int k = 0; k < 4; ++k) {
        int j = tr + k * 16;
        float4 v = *(const float4*)(Xl + (size_t)(j0 + j) * 1024 + i0 + tc * 4);
        T[tc * 4 + 0][j] = f2b(v.x);
        T[tc * 4 + 1][j] = f2b(v.y);
        T[tc * 4 + 2][j] = f2b(v.z);
        T[tc * 4 + 3][j] = f2b(v.w);
    }
    __syncthreads();
    const int wr_ = threadIdx.x >> 3;
    const int wc_ = threadIdx.x & 7;
#pragma unroll
    for (int k = 0; k < 2; ++k) {
        int i = wr_ + k * 32;
        u16 tmp[8];
#pragma unroll
        for (int e = 0; e < 8; ++e) tmp[e] = T[i][wc_ * 8 + e];
        *(ushort4*)(Yl + (size_t)(i0 + i) * 1024 + j0 + wc_ * 8)     = make_ushort4(tmp[0], tmp[1], tmp[2], tmp[3]);
        *(ushort4*)(Yl + (size_t)(i0 + i) * 1024 + j0 + wc_ * 8 + 4) = make_ushort4(tmp[4], tmp[5], tmp[6], tmp[7]);
    }
}

// ---------------- bcomb[l][o] = sum_j Wc2[l][o][j]*bc1[l][j] + bc2[l][o] (f32) ----------------
__global__ __launch_bounds__(256) void matvec_kernel(const float* __restrict__ W2, const float* __restrict__ b1,
                                                     const float* __restrict__ b2, float* __restrict__ outv)
{
    const int wid = threadIdx.x >> 6, lane = threadIdx.x & 63;
    int row = blockIdx.x * 4 + wid;
    int l = row >> 10, o = row & 1023;
    const float* wr_ = W2 + (size_t)l * 1024 * 1024 + (size_t)o * 1024;
    const float* b1l = b1 + l * 1024;
    float s = 0.f;
#pragma unroll
    for (int c = 0; c < 4; ++c) {
        float4 w = *(const float4*)(wr_ + c * 256 + lane * 4);
        float4 bv = *(const float4*)(b1l + c * 256 + lane * 4);
        s += w.x * bv.x + w.y * bv.y + w.z * bv.z + w.w * bv.w;
    }
#pragma unroll
    for (int m = 32; m >= 1; m >>= 1) s += __shfl_xor(s, m);
    if (lane == 0) outv[row] = s + b2[l * 1024 + o];
}

// ---------------- mask bitpack + per-row any-flag ----------------
__global__ __launch_bounds__(256) void mask_kernel(const int* __restrict__ am, u32* __restrict__ mw)
{
    size_t idx = (size_t)blockIdx.x * 256 + threadIdx.x;
    unsigned long long bal = __ballot(am[idx] == 0);
    int lane = threadIdx.x & 63;
    if (lane == 0)  mw[idx >> 5] = (u32)bal;
    if (lane == 32) mw[idx >> 5] = (u32)(bal >> 32);
}

__global__ __launch_bounds__(256) void rowflag_kernel(const u32* __restrict__ mw, u32* __restrict__ rf)
{
    int r = blockIdx.x * 256 + threadIdx.x;
    u32 o = 0;
#pragma unroll
    for (int i = 0; i < 32; ++i) o |= mw[r * 32 + i];
    rf[r] = o;
}

// ---------------- host-side orchestration ----------------
extern "C" void kernel_launch(void* const* d_in, const int* in_sizes, int n_in,
                              void* d_out, int out_size, void* d_ws, size_t ws_size,
                              hipStream_t stream)
{
    (void)in_sizes; (void)n_in; (void)out_size; (void)ws_size;

    const float* q_in  = (const float*)d_in[0];
    const float* k_in  = (const float*)d_in[1];
    const float* v_in  = (const float*)d_in[2];
    const int*   amask = (const int*)d_in[3];
    const float* Wqkv  = (const float*)d_in[4];
    const float* bqkv  = (const float*)d_in[5];
    const float* Wo    = (const float*)d_in[6];
    const float* bo    = (const float*)d_in[7];
    const float* ln1g  = (const float*)d_in[8];
    const float* ln1b  = (const float*)d_in[9];
    const float* ln2g  = (const float*)d_in[10];
    const float* ln2b  = (const float*)d_in[11];
    const float* Wc1   = (const float*)d_in[12];
    const float* bc1   = (const float*)d_in[13];
    const float* Wc2   = (const float*)d_in[14];
    const float* bc2   = (const float*)d_in[15];
    const float* lastg = (const float*)d_in[16];
    const float* lastb = (const float*)d_in[17];
    const float* Wfc   = (const float*)d_in[18];
    const float* bfc   = (const float*)d_in[19];
    float* out = (float*)d_out;

    char* base = (char*)d_ws;
    size_t off = 0;
    auto alloc = [&](size_t bytes) -> char* {
        char* p = base + off;
        off = (off + bytes + 255) & ~(size_t)255;
        return p;
    };
    const size_t M1 = 1024 * 1024;          // D*D
    const size_t MT = 8192 * 1024;          // B*S*D
    u16* wqkv_b = (u16*)alloc(6 * M1 * 2);
    u16* wo_b   = (u16*)alloc(2 * M1 * 2);
    u16* wcomb  = (u16*)alloc(2 * M1 * 2);  // (Wc2*Wc1) per layer
    u16* wfc_b  = (u16*)alloc(M1 * 2);
    float* bcomb = (float*)alloc(2 * 1024 * 4);
    float* zb    = (float*)alloc(1024 * 4); // zero bias
    u32* maskw  = (u32*)alloc(8192 * 32 * 4);
    u32* rowfl  = (u32*)alloc(8192 * 4);
    u16* t0 = (u16*)alloc(MT * 2);          // LN1 out / attn out
    u16* t1 = (u16*)alloc(MT * 2);          // post-Wo bf16 state
    u16* qh = (u16*)alloc(MT * 2);
    u16* kh = (u16*)alloc(MT * 2);
    u16* vt = (u16*)alloc(MT * 2);          // V^T: [1024 d_global][8192 s_global]
    u16* xb = (u16*)alloc(MT * 2);          // LN2 out (k1) / layer-0 v_in cvt
    u16* x2 = (u16*)alloc(MT * 2);          // k-state bf16 / layer-0 k_in cvt
    // prep-phase scratch aliases (consumed before qh/kh are first written):
    u16* wc1t  = qh;                        // Wc1^T bf16, 2*M1
    u16* wc2_b = kh;                        // Wc2 bf16, 2*M1

    // ---- weight prep ----
    cvt_kernel<<<6 * M1 / 1024, 256, 0, stream>>>(Wqkv, wqkv_b, (int)(6 * M1 / 4));
    cvt_kernel<<<2 * M1 / 1024, 256, 0, stream>>>(Wo,   wo_b,   (int)(2 * M1 / 4));
    cvt_kernel<<<M1 / 1024, 256, 0, stream>>>(Wfc, wfc_b, (int)(M1 / 4));
    cvt_kernel<<<2 * M1 / 1024, 256, 0, stream>>>(Wc2, wc2_b, (int)(2 * M1 / 4));
    cvtT_kernel<<<dim3(16, 16, 2), 256, 0, stream>>>(Wc1, wc1t);
    hipMemsetAsync(zb, 0, 1024 * 4, stream);
    gemm_z2<<<dim3(8, 8, 2), 256, 0, stream>>>(
        wc2_b, wc1t, zb, wcomb, 1.f,
        wc2_b + M1, wc1t + M1, zb, wcomb + M1, 1.f);
    matvec_kernel<<<512, 256, 0, stream>>>(Wc2, bc1, bc2, bcomb);
    mask_kernel<<<32768, 256, 0, stream>>>(amask, maskw);
    rowflag_kernel<<<32, 256, 0, stream>>>(maskw, rowfl);

    dim3 g8(8192 / 256, 1024 / 128);    // (32, 8) standard
    dim3 v8(1024 / 256, 8192 / 128);    // (4, 64) swapped V-projection
    dim3 gqk(8192 / 256, 1024 / 256, 2); // (32, 4, 2) paired Q+K 256^2
    const float QS = 0.125f * 1.44269504f;   // (1/sqrt(dk)) * log2(e): exp2-domain scores
    const int D = 1024;
    for (int i = 0; i < 2; ++i) {
        // LN1 -> t0 (bf16)
        if (i == 0) {
            ln_f<<<2048, 256, 0, stream>>>(q_in, ln1g, ln1b, t0);
            cvt_kernel<<<8192, 256, 0, stream>>>(k_in, x2, (int)(MT / 4));
            cvt_kernel<<<8192, 256, 0, stream>>>(v_in, xb, (int)(MT / 4));
        } else {
            ln_b<<<2048, 256, 0, stream>>>(x2, ln1g + i * D, ln1b + i * D, t0);
        }
        // Q (prescaled into exp2 domain) and K projections, paired 256^2 kernel
        gemm_qk256<<<gqk, 512, 0, stream>>>(
            t0, wqkv_b + (size_t)(i * 3 + 0) * M1, bqkv + (i * 3 + 0) * D, qh, QS,
            x2, wqkv_b + (size_t)(i * 3 + 1) * M1, bqkv + (i * 3 + 1) * D, kh, 1.f);
        // V projection, swapped: vt[d][s] = W_v · X^T  (row-bias)
        const u16* vin_b = (i == 0) ? xb : x2;
        gemm8<8 | 16, 8192><<<v8, 512, 0, stream>>>(wqkv_b + (size_t)(i * 3 + 2) * M1, vin_b,
                                                    bqkv + (i * 3 + 2) * D, nullptr, nullptr, vt, 1.f);
        // attention -> t0
        attn_kernel<<<dim3(128, 8), 512, 0, stream>>>(qh, kh, vt, maskw, rowfl, t0);
        // t1 = f2b(k_state + relu(attn @ Wo^T + bo))   (bf16 residual)
        gemm8<1 | 2 | 8, 1024><<<g8, 512, 0, stream>>>(t0, wo_b + (size_t)i * M1,
                                                       bo + i * D, x2, nullptr, t1, 1.f);
        // k1 = LN2(t1) -> xb (bf16)
        ln_b<<<2048, 256, 0, stream>>>(t1, ln2g + i * D, ln2b + i * D, xb);
        // folded FFN: x2 = f2b(k1 + k1 @ Wcomb^T + bcomb)   (res = xb itself)
        gemm8<2 | 8, 1024><<<g8, 512, 0, stream>>>(xb, wcomb + (size_t)i * M1,
                                                   bcomb + i * 1024, xb, nullptr, x2, 1.f);
    }
    // final LN + FC
    ln_b<<<2048, 256, 0, stream>>>(x2, lastg, lastb, t0);
    gemm8<4, 1024><<<g8, 512, 0, stream>>>(t0, wfc_b, bfc, nullptr, out, nullptr, 1.f);
}

// Round 16
// 470.068 us; speedup vs baseline: 1.0546x; 1.0169x over previous
//
#include <hip/hip_runtime.h>

typedef __attribute__((ext_vector_type(8))) short s8x;   // 8 x bf16 (raw bits)
typedef __attribute__((ext_vector_type(4))) float f4x;
typedef unsigned short u16;
typedef unsigned int u32;

#define DEV static __device__ __forceinline__

DEV u16 f2b(float f) {
    union { float f; u32 u; } v; v.f = f;
    u32 r = v.u + 0x7FFFu + ((v.u >> 16) & 1u);
    return (u16)(r >> 16);
}

DEV float b2f(u16 x) {
    union { u32 u; float f; } v; v.u = (u32)x << 16;
    return v.f;
}

DEV u32 pk2(float lo, float hi) {   // v_cvt_pk_bf16_f32: low16=lo, high16=hi
    u32 r;
    asm("v_cvt_pk_bf16_f32 %0, %1, %2" : "=v"(r) : "v"(lo), "v"(hi));
    return r;
}

DEV float exp2_raw(float x) {       // D = 2^x (v_exp_f32 native semantics)
    float r;
    asm("v_exp_f32 %0, %1" : "=v"(r) : "v"(x));
    return r;
}

DEV void gload16(const void* g, void* lds) {
    __builtin_amdgcn_global_load_lds(
        (const __attribute__((address_space(1))) void*)g,
        (__attribute__((address_space(3))) void*)lds, 16, 0, 0);
}

#define GK 1024
#define BM 128
#define BN 128
#define BK 64

// ---------------- 8-phase GEMM core pieces (T2 swizzle, T3/T4 counted vmcnt, T5 setprio) ----
// Swizzle (both-sides, rule #21): LDS[row][cd] = G[row][cd ^ (row&7)]; read chunk = want ^ (row&7).

DEV void stage_unit(const u16* __restrict__ g, char* l, int tid) {
    // one 16KB unit = 128 rows x 128B; 512 threads x 2 x 16B
#pragma unroll
    for (int i = 0; i < 2; ++i) {
        int db = i * 8192 + tid * 16;
        int row = db >> 7;
        int cs = ((db >> 4) & 7) ^ (row & 7);
        gload16(g + (size_t)row * 1024 + cs * 8, l + db);
    }
}

DEV s8x lds_frag(const char* Lbase, int row, int kk, int lg) {
    int cb = (kk * 64 + lg * 16) ^ ((row & 7) << 4);
    return *(const s8x*)(Lbase + row * 128 + cb);
}

// ---------------- gemm8: C[M,N] = A[M,K] @ W[N,K]^T, 256x128 tile, 8 waves ----------------
// FLAGS: 1=RELU, 2=RES (bf16 residual add after relu), 4=WF (f32 out), 8=WB (bf16 out), 16=row-bias
// Mid-tile barriers removed (intra-tile reads hit stable buffers; staging protected by the
// counted end-of-tile vmcnt + single barrier) -> waves drift, MFMA overlaps neighbor ds_reads.
template<int FLAGS, int NN>
__global__ __launch_bounds__(512, 2) void gemm8(
    const u16* __restrict__ A, const u16* __restrict__ W,
    const float* __restrict__ bias, const u16* __restrict__ res,
    float* __restrict__ outf, u16* __restrict__ outb, float scl)
{
    constexpr bool RELU = (FLAGS & 1) != 0;
    constexpr bool RES  = (FLAGS & 2) != 0;
    constexpr bool WF   = (FLAGS & 4) != 0;
    constexpr bool WB   = (FLAGS & 8) != 0;
    constexpr bool RBIA = (FLAGS & 16) != 0;

    __shared__ __attribute__((aligned(16))) u16 As[3][256 * 64];   // 96 KB
    __shared__ __attribute__((aligned(16))) u16 Bs[3][128 * 64];   // 48 KB

    const int tid = threadIdx.x, lane = tid & 63, wid = tid >> 6;
    const int l15 = lane & 15, lg = lane >> 4;
    const int wm = wid >> 1, wn = wid & 1;
    const int bm = blockIdx.x, bn = blockIdx.y;

    const u16* Ab = A + (size_t)bm * 256 * GK;
    const u16* Wb = W + (size_t)bn * 128 * GK;

    f4x acc[4][4];
#pragma unroll
    for (int i = 0; i < 4; ++i)
#pragma unroll
        for (int j = 0; j < 4; ++j) { f4x z = {0.f, 0.f, 0.f, 0.f}; acc[i][j] = z; }

    char* a0 = (char*)As[0]; char* a1 = (char*)As[1]; char* a2 = (char*)As[2];
    char* b0 = (char*)Bs[0]; char* b1 = (char*)Bs[1]; char* b2 = (char*)Bs[2];

    stage_unit(Ab + 0 * 64,                 a0,        tid);
    stage_unit(Ab + 128 * GK + 0 * 64,      a0 + 16384, tid);
    stage_unit(Wb + 0 * 64,                 b0,        tid);
    stage_unit(Ab + 1 * 64,                 a1,        tid);
    stage_unit(Ab + 128 * GK + 1 * 64,      a1 + 16384, tid);
    stage_unit(Wb + 1 * 64,                 b1,        tid);
    asm volatile("s_waitcnt vmcnt(6)" ::: "memory");
    __builtin_amdgcn_s_barrier();

    for (int t = 0; t < 16; ++t) {
        const bool st = (t < 14);
        s8x bfr[4][2], afr[2][2];
#pragma unroll
        for (int ni = 0; ni < 4; ++ni)
#pragma unroll
            for (int kk = 0; kk < 2; ++kk)
                bfr[ni][kk] = lds_frag(b0, wn * 64 + ni * 16 + l15, kk, lg);
#pragma unroll
        for (int mi = 0; mi < 2; ++mi)
#pragma unroll
            for (int kk = 0; kk < 2; ++kk)
                afr[mi][kk] = lds_frag(a0, wm * 64 + mi * 16 + l15, kk, lg);
        if (st) {
            stage_unit(Ab + (t + 2) * 64,            a2,         tid);
            stage_unit(Ab + 128 * GK + (t + 2) * 64, a2 + 16384, tid);
        }
        asm volatile("s_waitcnt lgkmcnt(0)" ::: "memory");
        __builtin_amdgcn_sched_barrier(0);
        __builtin_amdgcn_s_setprio(1);
#pragma unroll
        for (int kk = 0; kk < 2; ++kk)
#pragma unroll
            for (int mi = 0; mi < 2; ++mi)
#pragma unroll
                for (int ni = 0; ni < 4; ++ni)
                    acc[mi][ni] = __builtin_amdgcn_mfma_f32_16x16x32_bf16(afr[mi][kk], bfr[ni][kk], acc[mi][ni], 0, 0, 0);
        __builtin_amdgcn_s_setprio(0);

        s8x afr2[2][2];
#pragma unroll
        for (int mi = 0; mi < 2; ++mi)
#pragma unroll
            for (int kk = 0; kk < 2; ++kk)
                afr2[mi][kk] = lds_frag(a0, wm * 64 + (mi + 2) * 16 + l15, kk, lg);
        if (st) stage_unit(Wb + (t + 2) * 64, b2, tid);
        asm volatile("s_waitcnt lgkmcnt(0)" ::: "memory");
        __builtin_amdgcn_sched_barrier(0);
        __builtin_amdgcn_s_setprio(1);
#pragma unroll
        for (int kk = 0; kk < 2; ++kk)
#pragma unroll
            for (int mi = 0; mi < 2; ++mi)
#pragma unroll
                for (int ni = 0; ni < 4; ++ni)
                    acc[mi + 2][ni] = __builtin_amdgcn_mfma_f32_16x16x32_bf16(afr2[mi][kk], bfr[ni][kk], acc[mi + 2][ni], 0, 0, 0);
        __builtin_amdgcn_s_setprio(0);
        if (st) asm volatile("s_waitcnt vmcnt(6)" ::: "memory");
        else    asm volatile("s_waitcnt vmcnt(0)" ::: "memory");
        __builtin_amdgcn_s_barrier();

        char* tA = a0; a0 = a1; a1 = a2; a2 = tA;
        char* tB = b0; b0 = b1; b1 = b2; b2 = tB;
    }

#pragma unroll
    for (int ni = 0; ni < 4; ++ni) {
        int gcol = bn * 128 + wn * 64 + ni * 16 + l15;
        float bvc = RBIA ? 0.f : bias[gcol];
#pragma unroll
        for (int mi = 0; mi < 4; ++mi) {
            int grow0 = bm * 256 + wm * 64 + mi * 16 + lg * 4;
#pragma unroll
            for (int r = 0; r < 4; ++r) {
                float bv = RBIA ? bias[grow0 + r] : bvc;
                float v = (acc[mi][ni][r] + bv) * scl;
                if (RELU) v = fmaxf(v, 0.f);
                size_t oidx = (size_t)(grow0 + r) * NN + gcol;
                if (RES) v += b2f(res[oidx]);
                if (WF) outf[oidx] = v;
                if (WB) outb[oidx] = f2b(v);
            }
        }
    }
}

// ---------------- gemm_qk256: z=2-paired 256x256-tile GEMM (Q and K projections) ----------------
// Mid-tile barriers removed (same safety argument as gemm8).
__global__ __launch_bounds__(512, 2) void gemm_qk256(
    const u16* __restrict__ A0p, const u16* __restrict__ W0p, const float* __restrict__ b0p,
    u16* __restrict__ o0p, float s0,
    const u16* __restrict__ A1p, const u16* __restrict__ W1p, const float* __restrict__ b1p,
    u16* __restrict__ o1p, float s1)
{
    const int z = blockIdx.z;
    const u16* A = z ? A1p : A0p;
    const u16* W = z ? W1p : W0p;
    const float* bias = z ? b1p : b0p;
    u16* outb = z ? o1p : o0p;
    const float scl = z ? s1 : s0;

    __shared__ __attribute__((aligned(16))) u16 As[3][256 * 64];   // 96 KB
    __shared__ __attribute__((aligned(16))) u16 Bs[2][256 * 64];   // 64 KB

    const int tid = threadIdx.x, lane = tid & 63, wid = tid >> 6;
    const int l15 = lane & 15, lg = lane >> 4;
    const int wm = wid >> 2;
    const int wn = wid & 3;
    const int bm = blockIdx.x, bn = blockIdx.y;

    const u16* Ab = A + (size_t)bm * 256 * GK;
    const u16* Wb = W + (size_t)bn * 256 * GK;

    f4x acc[8][4];
#pragma unroll
    for (int i = 0; i < 8; ++i)
#pragma unroll
        for (int j = 0; j < 4; ++j) { f4x zz = {0.f, 0.f, 0.f, 0.f}; acc[i][j] = zz; }

    char* a0 = (char*)As[0]; char* a1 = (char*)As[1]; char* a2 = (char*)As[2];
    char* b0 = (char*)Bs[0]; char* b1 = (char*)Bs[1];

    stage_unit(Ab + 0 * 64,            a0,         tid);
    stage_unit(Ab + 128 * GK + 0 * 64, a0 + 16384, tid);
    stage_unit(Wb + 0 * 64,            b0,         tid);
    stage_unit(Wb + 128 * GK + 0 * 64, b0 + 16384, tid);
    stage_unit(Ab + 1 * 64,            a1,         tid);
    stage_unit(Ab + 128 * GK + 1 * 64, a1 + 16384, tid);
    asm volatile("s_waitcnt vmcnt(4)" ::: "memory");
    __builtin_amdgcn_s_barrier();

    const char* aW = nullptr;
    const char* bW = nullptr;
    for (int t = 0; t < 16; ++t) {
        aW = a0 + wm * 16384;
        bW = b0 + (wn >> 1) * 16384;
        const int brow0 = (wn & 1) * 64;

        s8x bfr[4][2], afr[4][2];
#pragma unroll
        for (int ni = 0; ni < 4; ++ni)
#pragma unroll
            for (int kk = 0; kk < 2; ++kk)
                bfr[ni][kk] = lds_frag(bW, brow0 + ni * 16 + l15, kk, lg);
#pragma unroll
        for (int mi = 0; mi < 4; ++mi)
#pragma unroll
            for (int kk = 0; kk < 2; ++kk)
                afr[mi][kk] = lds_frag(aW, mi * 16 + l15, kk, lg);
        if (t + 1 < 16) {
            stage_unit(Wb + (t + 1) * 64,            b1,         tid);
            stage_unit(Wb + 128 * GK + (t + 1) * 64, b1 + 16384, tid);
        }
        asm volatile("s_waitcnt lgkmcnt(0)" ::: "memory");
        __builtin_amdgcn_sched_barrier(0);
        __builtin_amdgcn_s_setprio(1);
#pragma unroll
        for (int kk = 0; kk < 2; ++kk)
#pragma unroll
            for (int mi = 0; mi < 4; ++mi)
#pragma unroll
                for (int ni = 0; ni < 4; ++ni)
                    acc[mi][ni] = __builtin_amdgcn_mfma_f32_16x16x32_bf16(afr[mi][kk], bfr[ni][kk], acc[mi][ni], 0, 0, 0);
        __builtin_amdgcn_s_setprio(0);

        s8x afr2[4][2];
#pragma unroll
        for (int mi = 0; mi < 4; ++mi)
#pragma unroll
            for (int kk = 0; kk < 2; ++kk)
                afr2[mi][kk] = lds_frag(aW, (mi + 4) * 16 + l15, kk, lg);
        if (t + 2 < 16) {
            stage_unit(Ab + (t + 2) * 64,            a2,         tid);
            stage_unit(Ab + 128 * GK + (t + 2) * 64, a2 + 16384, tid);
        }
        asm volatile("s_waitcnt lgkmcnt(0)" ::: "memory");
        __builtin_amdgcn_sched_barrier(0);
        __builtin_amdgcn_s_setprio(1);
#pragma unroll
        for (int kk = 0; kk < 2; ++kk)
#pragma unroll
            for (int mi = 0; mi < 4; ++mi)
#pragma unroll
                for (int ni = 0; ni < 4; ++ni)
                    acc[mi + 4][ni] = __builtin_amdgcn_mfma_f32_16x16x32_bf16(afr2[mi][kk], bfr[ni][kk], acc[mi + 4][ni], 0, 0, 0);
        __builtin_amdgcn_s_setprio(0);

        if (t <= 13)      asm volatile("s_waitcnt vmcnt(4)" ::: "memory");
        else if (t == 14) asm volatile("s_waitcnt vmcnt(0)" ::: "memory");
        __builtin_amdgcn_s_barrier();

        char* tA = a0; a0 = a1; a1 = a2; a2 = tA;
        char* tB = b0; b0 = b1; b1 = tB;
    }

#pragma unroll
    for (int ni = 0; ni < 4; ++ni) {
        int gcol = bn * 256 + wn * 64 + ni * 16 + l15;
        float bvc = bias[gcol];
#pragma unroll
        for (int mi = 0; mi < 8; ++mi) {
            int grow0 = bm * 256 + wm * 128 + mi * 16 + lg * 4;
#pragma unroll
            for (int r = 0; r < 4; ++r) {
                float v = (acc[mi][ni][r] + bvc) * scl;
                outb[(size_t)(grow0 + r) * 1024 + gcol] = f2b(v);
            }
        }
    }
}

// ---- z-batched 2-phase variant (weight-prep only): out = f2b((acc + bias) * scl) ----
__global__ __launch_bounds__(256) void gemm_z2(
    const u16* __restrict__ A0, const u16* __restrict__ W0, const float* __restrict__ b0,
    u16* __restrict__ o0, float s0,
    const u16* __restrict__ A1, const u16* __restrict__ W1, const float* __restrict__ b1,
    u16* __restrict__ o1, float s1)
{
    const int z = blockIdx.z;
    const u16* A = z ? A1 : A0;
    const u16* W = z ? W1 : W0;
    const float* bias = z ? b1 : b0;
    u16* outb = z ? o1 : o0;
    const float scl = z ? s1 : s0;

    __shared__ __attribute__((aligned(16))) u16 As[2][BM * BK];
    __shared__ __attribute__((aligned(16))) u16 Bs[2][BN * BK];

    const int tid  = threadIdx.x;
    const int lane = tid & 63;
    const int wid  = tid >> 6;
    const int wr = wid >> 1, wc = wid & 1;
    const int bm = blockIdx.x, bn = blockIdx.y;
    const int l15 = lane & 15;
    const int lg  = lane >> 4;

    const u16* Ab = A + (size_t)bm * BM * GK;
    const u16* Wb = W + (size_t)bn * BN * GK;

    const int prow = tid >> 3;
    const int pcol = (tid & 7) * 8;

    f4x acc[4][4];
#pragma unroll
    for (int i = 0; i < 4; ++i)
#pragma unroll
        for (int j = 0; j < 4; ++j) { f4x z_ = {0.f, 0.f, 0.f, 0.f}; acc[i][j] = z_; }

#pragma unroll
    for (int c = 0; c < 4; ++c) {
        int row = c * 32 + prow;
        gload16(Ab + (size_t)row * GK + pcol, &As[0][row * BK + pcol]);
    }
#pragma unroll
    for (int c = 0; c < 4; ++c) {
        int row = c * 32 + prow;
        gload16(Wb + (size_t)row * GK + pcol, &Bs[0][row * BK + pcol]);
    }

    const int nkt = GK / BK;
    int cur = 0;
    for (int kt = 0; kt < nkt; ++kt) {
        __syncthreads();
        if (kt + 1 < nkt) {
            const u16* Ak = Ab + (kt + 1) * BK;
            const u16* Wk = Wb + (kt + 1) * BK;
#pragma unroll
            for (int c = 0; c < 4; ++c) {
                int row = c * 32 + prow;
                gload16(Ak + (size_t)row * GK + pcol, &As[cur ^ 1][row * BK + pcol]);
            }
#pragma unroll
            for (int c = 0; c < 4; ++c) {
                int row = c * 32 + prow;
                gload16(Wk + (size_t)row * GK + pcol, &Bs[cur ^ 1][row * BK + pcol]);
            }
        }
        const u16* Ac = As[cur];
        const u16* Bc = Bs[cur];
#pragma unroll
        for (int kk = 0; kk < 2; ++kk) {
            s8x a[4], b[4];
#pragma unroll
            for (int mi = 0; mi < 4; ++mi)
                a[mi] = *(const s8x*)(Ac + (wr * 64 + mi * 16 + l15) * BK + kk * 32 + lg * 8);
#pragma unroll
            for (int ni = 0; ni < 4; ++ni)
                b[ni] = *(const s8x*)(Bc + (wc * 64 + ni * 16 + l15) * BK + kk * 32 + lg * 8);
#pragma unroll
            for (int mi = 0; mi < 4; ++mi)
#pragma unroll
                for (int ni = 0; ni < 4; ++ni)
                    acc[mi][ni] = __builtin_amdgcn_mfma_f32_16x16x32_bf16(a[mi], b[ni], acc[mi][ni], 0, 0, 0);
        }
        cur ^= 1;
    }

#pragma unroll
    for (int ni = 0; ni < 4; ++ni) {
        int gcol = bn * BN + wc * 64 + ni * 16 + l15;
        float bvc = bias[gcol];
#pragma unroll
        for (int mi = 0; mi < 4; ++mi) {
            int grow0 = bm * BM + wr * 64 + mi * 16 + lg * 4;
#pragma unroll
            for (int r = 0; r < 4; ++r) {
                float v = (acc[mi][ni][r] + bvc) * scl;
                outb[(size_t)(grow0 + r) * 1024 + gcol] = f2b(v);
            }
        }
    }
}

// ---------------- Attention v9 (round-13 best): 3-deep counted pipeline, no-clip exp2, ----
// MFMA row-sum via ones B-frag, Ps LDS round-trip, full unroll.
__global__ __launch_bounds__(512) void attn_kernel(
    const u16* __restrict__ Qm, const u16* __restrict__ Km, const u16* __restrict__ Vt,
    const u32* __restrict__ maskw, const u32* __restrict__ rowfl,
    u16* __restrict__ Om)
{
    const int bh = blockIdx.x;
    const int b  = bh >> 4;
    const int h  = bh & 15;
    const int qt = blockIdx.y;
    const int tid = threadIdx.x, lane = tid & 63, wid = tid >> 6;
    const int l15 = lane & 15, lg = lane >> 4;

    __shared__ __attribute__((aligned(16))) u16 Ks[3][64 * 64];   // 24 KB
    __shared__ __attribute__((aligned(16))) u16 Vs[3][64 * 64];   // 24 KB
    __shared__ __attribute__((aligned(16))) u16 Ps[8][16][64];    // 16 KB
    __shared__ int anymask;

    const size_t rowbase = (size_t)b * 1024;
    const int hoff = h * 64;

    if (tid == 0) anymask = 0;

    const int so   = tid * 16;
    const int srow = so >> 7;
    const int sch  = ((so >> 4) & 7) ^ (srow & 7);
    const int vswz = (l15 & 7) << 4;

    const u16* Kbase = Km + rowbase * 1024 + hoff + (size_t)srow * 1024 + sch * 8;
    const u16* Vbase = Vt + (size_t)(hoff + srow) * 8192 + b * 1024 + sch * 8;

    // prologue: stage tiles 0 and 1
    gload16(Kbase + 0 * 64 * 1024, (char*)Ks[0] + so);
    gload16(Vbase + 0 * 64,        (char*)Vs[0] + so);
    gload16(Kbase + 1 * 64 * 1024, (char*)Ks[1] + so);
    gload16(Vbase + 1 * 64,        (char*)Vs[1] + so);

    const int qrow = qt * 128 + wid * 16 + l15;
    s8x qf[2];
#pragma unroll
    for (int kk = 0; kk < 2; ++kk)
        qf[kk] = *(const s8x*)(Qm + (rowbase + qrow) * 1024 + hoff + kk * 32 + lg * 8);

    __syncthreads();   // anymask = 0 visible
    if (tid < 128) {
        if (rowfl[rowbase + qt * 128 + tid]) atomicOr(&anymask, 1);
    }

    f4x o[4];
#pragma unroll
    for (int d = 0; d < 4; ++d) { f4x z = {0.f, 0.f, 0.f, 0.f}; o[d] = z; }
    f4x osum = {0.f, 0.f, 0.f, 0.f};
    const s8x ones = {(short)0x3F80, (short)0x3F80, (short)0x3F80, (short)0x3F80,
                      (short)0x3F80, (short)0x3F80, (short)0x3F80, (short)0x3F80};

    asm volatile("s_waitcnt vmcnt(0)" ::: "memory");   // tiles 0,1 + qf + rowfl done
    __syncthreads();                                    // staging + atomicOr visible
    const int am = anymask;

#pragma unroll
    for (int kt = 0; kt < 16; ++kt) {
        const char* kc = (const char*)Ks[kt % 3];
        const char* vc = (const char*)Vs[kt % 3];
        // T14/T3: issue tile kt+2 staging into the buffer freed at kt-1's barrier
        if (kt + 2 < 16) {
            gload16(Kbase + (size_t)(kt + 2) * 64 * 1024, (char*)Ks[(kt + 2) % 3] + so);
            gload16(Vbase + (kt + 2) * 64,                (char*)Vs[(kt + 2) % 3] + so);
        }

        // swapped QK^T: C[k][q]; scores in log2 units (Q prescaled by log2e/8)
        f4x sc[4];
#pragma unroll
        for (int ni = 0; ni < 4; ++ni) { f4x z = {0.f, 0.f, 0.f, 0.f}; sc[ni] = z; }
        __builtin_amdgcn_s_setprio(1);
#pragma unroll
        for (int kk = 0; kk < 2; ++kk) {
#pragma unroll
            for (int ni = 0; ni < 4; ++ni) {
                int row = ni * 16 + l15;
                int cb  = (kk * 64 + lg * 16) ^ ((row & 7) << 4);
                s8x kf = *(const s8x*)(kc + row * 128 + cb);
                sc[ni] = __builtin_amdgcn_mfma_f32_16x16x32_bf16(kf, qf[kk], sc[ni], 0, 0, 0);
            }
        }
        __builtin_amdgcn_s_setprio(0);

        if (am) {
            int qg = qt * 128 + wid * 16 + l15;
#pragma unroll
            for (int ni = 0; ni < 4; ++ni)
#pragma unroll
                for (int r = 0; r < 4; ++r) {
                    int kcol = kt * 64 + ni * 16 + lg * 4 + r;
                    u32 wb_ = maskw[(rowbase + qg) * 32 + (kcol >> 5)];
                    if (wb_ & (1u << (kcol & 31))) sc[ni][r] = -1e9f;
                }
        }

        // p = 2^s raw (no clip; masked -1e9 underflows to 0)
#pragma unroll
        for (int ni = 0; ni < 4; ++ni)
#pragma unroll
            for (int r = 0; r < 4; ++r)
                sc[ni][r] = exp2_raw(sc[ni][r]);

        // pack P (bf16) -> per-wave swizzled LDS, read back as A-frag
#pragma unroll
        for (int ni = 0; ni < 4; ++ni) {
            uint2 w; w.x = pk2(sc[ni][0], sc[ni][1]); w.y = pk2(sc[ni][2], sc[ni][3]);
            *(uint2*)((char*)&Ps[wid][l15][0] + ((ni * 32 + lg * 8) ^ vswz)) = w;
        }
        s8x pa[2];
#pragma unroll
        for (int kk = 0; kk < 2; ++kk)
            pa[kk] = *(const s8x*)((const char*)&Ps[wid][l15][0] + ((kk * 64 + lg * 16) ^ vswz));

        __builtin_amdgcn_s_setprio(1);
        // denominator on the matrix pipe: osum[q] += sum_k P[q][k]
#pragma unroll
        for (int kk = 0; kk < 2; ++kk)
            osum = __builtin_amdgcn_mfma_f32_16x16x32_bf16(pa[kk], ones, osum, 0, 0, 0);
#pragma unroll
        for (int dt = 0; dt < 4; ++dt)
#pragma unroll
            for (int kk = 0; kk < 2; ++kk) {
                int row = dt * 16 + l15;
                int cb  = (kk * 64 + lg * 16) ^ ((row & 7) << 4);
                s8x vf = *(const s8x*)(vc + row * 128 + cb);
                o[dt] = __builtin_amdgcn_mfma_f32_16x16x32_bf16(pa[kk], vf, o[dt], 0, 0, 0);
            }
        __builtin_amdgcn_s_setprio(0);

        // counted wait: tile kt+1 resident; kt+2's 2 loads stay in flight across barrier
        if (kt + 2 < 16)      asm volatile("s_waitcnt vmcnt(2)" ::: "memory");
        else if (kt + 1 < 16) asm volatile("s_waitcnt vmcnt(0)" ::: "memory");
        __builtin_amdgcn_s_barrier();
    }

    // osum C-layout: row q = lg*4 + r -> exactly the indexing o[dt][r] needs (no shfl)
    float rlr[4];
#pragma unroll
    for (int r = 0; r < 4; ++r) rlr[r] = 1.f / osum[r];
#pragma unroll
    for (int dt = 0; dt < 4; ++dt) {
        int gc = hoff + dt * 16 + l15;
#pragma unroll
        for (int r = 0; r < 4; ++r) {
            int gr = qt * 128 + wid * 16 + lg * 4 + r;
            Om[(rowbase + gr) * 1024 + gc] = f2b(o[dt][r] * rlr[r]);
        }
    }
}

// ---------------- LayerNorm, f32 input -> bf16 output (layer-0 LN1 only) ----------------
__global__ __launch_bounds__(256) void ln_f(
    const float* __restrict__ x, const float* __restrict__ g, const float* __restrict__ bb,
    u16* __restrict__ yb)
{
    const int wid = threadIdx.x >> 6, lane = threadIdx.x & 63;
    const size_t row = (size_t)blockIdx.x * 4 + wid;
    const float* xr = x + row * 1024;
    float4 v[4];
    float s = 0.f, s2 = 0.f;
#pragma unroll
    for (int c = 0; c < 4; ++c) {
        v[c] = *(const float4*)(xr + c * 256 + lane * 4);
        s  += v[c].x + v[c].y + v[c].z + v[c].w;
        s2 += v[c].x * v[c].x + v[c].y * v[c].y + v[c].z * v[c].z + v[c].w * v[c].w;
    }
#pragma unroll
    for (int m = 32; m >= 1; m >>= 1) { s += __shfl_xor(s, m); s2 += __shfl_xor(s2, m); }
    float mean = s * (1.f / 1024.f);
    float var  = s2 * (1.f / 1024.f) - mean * mean;
    float rs = rsqrtf(var + 1e-8f);
#pragma unroll
    for (int c = 0; c < 4; ++c) {
        int col = c * 256 + lane * 4;
        float4 gv = *(const float4*)(g + col);
        float4 bv = *(const float4*)(bb + col);
        ushort4 o4 = make_ushort4(
            f2b((v[c].x - mean) * rs * gv.x + bv.x),
            f2b((v[c].y - mean) * rs * gv.y + bv.y),
            f2b((v[c].z - mean) * rs * gv.z + bv.z),
            f2b((v[c].w - mean) * rs * gv.w + bv.w));
        *(ushort4*)(yb + row * 1024 + col) = o4;
    }
}

// ---------------- LayerNorm, bf16 input -> bf16 output ----------------
__global__ __launch_bounds__(256) void ln_b(
    const u16* __restrict__ x, const float* __restrict__ g, const float* __restrict__ bb,
    u16* __restrict__ yb)
{
    const int wid = threadIdx.x >> 6, lane = threadIdx.x & 63;
    const size_t row = (size_t)blockIdx.x * 4 + wid;
    const u16* xr = x + row * 1024 + lane * 16;
    s8x v0 = *(const s8x*)xr;
    s8x v1 = *(const s8x*)(xr + 8);
    float f[16];
    float s = 0.f, s2 = 0.f;
#pragma unroll
    for (int j = 0; j < 8; ++j) { f[j] = b2f((u16)v0[j]); f[8 + j] = b2f((u16)v1[j]); }
#pragma unroll
    for (int j = 0; j < 16; ++j) { s += f[j]; s2 += f[j] * f[j]; }
#pragma unroll
    for (int m = 32; m >= 1; m >>= 1) { s += __shfl_xor(s, m); s2 += __shfl_xor(s2, m); }
    float mean = s * (1.f / 1024.f);
    float var  = s2 * (1.f / 1024.f) - mean * mean;
    float rs = rsqrtf(var + 1e-8f);
    const int col0 = lane * 16;
    u16 ov[16];
#pragma unroll
    for (int c = 0; c < 4; ++c) {
        float4 gv = *(const float4*)(g + col0 + c * 4);
        float4 bv = *(const float4*)(bb + col0 + c * 4);
        ov[c * 4 + 0] = f2b((f[c * 4 + 0] - mean) * rs * gv.x + bv.x);
        ov[c * 4 + 1] = f2b((f[c * 4 + 1] - mean) * rs * gv.y + bv.y);
        ov[c * 4 + 2] = f2b((f[c * 4 + 2] - mean) * rs * gv.z + bv.z);
        ov[c * 4 + 3] = f2b((f[c * 4 + 3] - mean) * rs * gv.w + bv.w);
    }
    u16* yr = yb + row * 1024 + col0;
    *(ushort4*)(yr + 0)  = make_ushort4(ov[0], ov[1], ov[2], ov[3]);
    *(ushort4*)(yr + 4)  = make_ushort4(ov[4], ov[5], ov[6], ov[7]);
    *(ushort4*)(yr + 8)  = make_ushort4(ov[8], ov[9], ov[10], ov[11]);
    *(ushort4*)(yr + 12) = make_ushort4(ov[12], ov[13], ov[14], ov[15]);
}

// ---------------- f32 -> bf16 convert ----------------
__global__ __launch_bounds__(256) void cvt_kernel(const float* __restrict__ x, u16* __restrict__ y, int n4)
{
    int i = blockIdx.x * 256 + threadIdx.x;
    if (i < n4) {
        float4 v = *(const float4*)(x + (size_t)i * 4);
        ushort4 o = make_ushort4(f2b(v.x), f2b(v.y), f2b(v.z), f2b(v.w));
        *(ushort4*)(y + (size_t)i * 4) = o;
    }
}

// ---------------- transpose-convert: Y[l][i][j] = bf16(X[l][j][i]), 1024x1024/layer ----------------
__global__ __launch_bounds__(256) void cvtT_kernel(const float* __restrict__ X, u16* __restrict__ Y)
{
    __shared__ u16 T[64][65];
    const int l = blockIdx.z;
    const int j0 = blockIdx.y * 64;
    const int i0 = blockIdx.x * 64;
    const float* Xl = X + (size_t)l * 1024 * 1024;
    u16* Yl = Y + (size_t)l * 1024 * 1024;
    const int tr = threadIdx.x >> 4;
    const int tc = threadIdx.x & 15;
#pragma unroll
    for (int k = 0; k < 4; ++k) {
        int j = tr + k * 16;
        float4 v = *(const float4*)(Xl + (size_t)(j0 + j) * 1024 + i0 + tc * 4);
        T[tc * 4 + 0][j] = f2b(v.x);
        T[tc * 4 + 1][j] = f2b(v.y);
        T[tc * 4 + 2][j] = f2b(v.z);
        T[tc * 4 + 3][j] = f2b(v.w);
    }
    __syncthreads();
    const int wr_ = threadIdx.x >> 3;
    const int wc_ = threadIdx.x & 7;
#pragma unroll
    for (int k = 0; k < 2; ++k) {
        int i = wr_ + k * 32;
        u16 tmp[8];
#pragma unroll
        for (int e = 0; e < 8; ++e) tmp[e] = T[i][wc_ * 8 + e];
        *(ushort4*)(Yl + (size_t)(i0 + i) * 1024 + j0 + wc_ * 8)     = make_ushort4(tmp[0], tmp[1], tmp[2], tmp[3]);
        *(ushort4*)(Yl + (size_t)(i0 + i) * 1024 + j0 + wc_ * 8 + 4) = make_ushort4(tmp[4], tmp[5], tmp[6], tmp[7]);
    }
}

// ---------------- bcomb[l][o] = sum_j Wc2[l][o][j]*bc1[l][j] + bc2[l][o] (f32) ----------------
__global__ __launch_bounds__(256) void matvec_kernel(const float* __restrict__ W2, const float* __restrict__ b1,
                                                     const float* __restrict__ b2, float* __restrict__ outv)
{
    const int wid = threadIdx.x >> 6, lane = threadIdx.x & 63;
    int row = blockIdx.x * 4 + wid;
    int l = row >> 10, o = row & 1023;
    const float* wr_ = W2 + (size_t)l * 1024 * 1024 + (size_t)o * 1024;
    const float* b1l = b1 + l * 1024;
    float s = 0.f;
#pragma unroll
    for (int c = 0; c < 4; ++c) {
        float4 w = *(const float4*)(wr_ + c * 256 + lane * 4);
        float4 bv = *(const float4*)(b1l + c * 256 + lane * 4);
        s += w.x * bv.x + w.y * bv.y + w.z * bv.z + w.w * bv.w;
    }
#pragma unroll
    for (int m = 32; m >= 1; m >>= 1) s += __shfl_xor(s, m);
    if (lane == 0) outv[row] = s + b2[l * 1024 + o];
}

// ---------------- mask bitpack + per-row any-flag ----------------
__global__ __launch_bounds__(256) void mask_kernel(const int* __restrict__ am, u32* __restrict__ mw)
{
    size_t idx = (size_t)blockIdx.x * 256 + threadIdx.x;
    unsigned long long bal = __ballot(am[idx] == 0);
    int lane = threadIdx.x & 63;
    if (lane == 0)  mw[idx >> 5] = (u32)bal;
    if (lane == 32) mw[idx >> 5] = (u32)(bal >> 32);
}

__global__ __launch_bounds__(256) void rowflag_kernel(const u32* __restrict__ mw, u32* __restrict__ rf)
{
    int r = blockIdx.x * 256 + threadIdx.x;
    u32 o = 0;
#pragma unroll
    for (int i = 0; i < 32; ++i) o |= mw[r * 32 + i];
    rf[r] = o;
}

// ---------------- host-side orchestration ----------------
extern "C" void kernel_launch(void* const* d_in, const int* in_sizes, int n_in,
                              void* d_out, int out_size, void* d_ws, size_t ws_size,
                              hipStream_t stream)
{
    (void)in_sizes; (void)n_in; (void)out_size; (void)ws_size;

    const float* q_in  = (const float*)d_in[0];
    const float* k_in  = (const float*)d_in[1];
    const float* v_in  = (const float*)d_in[2];
    const int*   amask = (const int*)d_in[3];
    const float* Wqkv  = (const float*)d_in[4];
    const float* bqkv  = (const float*)d_in[5];
    const float* Wo    = (const float*)d_in[6];
    const float* bo    = (const float*)d_in[7];
    const float* ln1g  = (const float*)d_in[8];
    const float* ln1b  = (const float*)d_in[9];
    const float* ln2g  = (const float*)d_in[10];
    const float* ln2b  = (const float*)d_in[11];
    const float* Wc1   = (const float*)d_in[12];
    const float* bc1   = (const float*)d_in[13];
    const float* Wc2   = (const float*)d_in[14];
    const float* bc2   = (const float*)d_in[15];
    const float* lastg = (const float*)d_in[16];
    const float* lastb = (const float*)d_in[17];
    const float* Wfc   = (const float*)d_in[18];
    const float* bfc   = (const float*)d_in[19];
    float* out = (float*)d_out;

    char* base = (char*)d_ws;
    size_t off = 0;
    auto alloc = [&](size_t bytes) -> char* {
        char* p = base + off;
        off = (off + bytes + 255) & ~(size_t)255;
        return p;
    };
    const size_t M1 = 1024 * 1024;          // D*D
    const size_t MT = 8192 * 1024;          // B*S*D
    u16* wqkv_b = (u16*)alloc(6 * M1 * 2);
    u16* wo_b   = (u16*)alloc(2 * M1 * 2);
    u16* wcomb  = (u16*)alloc(2 * M1 * 2);  // (Wc2*Wc1) per layer
    u16* wfc_b  = (u16*)alloc(M1 * 2);
    float* bcomb = (float*)alloc(2 * 1024 * 4);
    float* zb    = (float*)alloc(1024 * 4); // zero bias
    u32* maskw  = (u32*)alloc(8192 * 32 * 4);
    u32* rowfl  = (u32*)alloc(8192 * 4);
    u16* t0 = (u16*)alloc(MT * 2);          // LN1 out / attn out
    u16* t1 = (u16*)alloc(MT * 2);          // post-Wo bf16 state
    u16* qh = (u16*)alloc(MT * 2);
    u16* kh = (u16*)alloc(MT * 2);
    u16* vt = (u16*)alloc(MT * 2);          // V^T: [1024 d_global][8192 s_global]
    u16* xb = (u16*)alloc(MT * 2);          // LN2 out (k1) / layer-0 v_in cvt
    u16* x2 = (u16*)alloc(MT * 2);          // k-state bf16 / layer-0 k_in cvt
    // prep-phase scratch aliases (consumed before qh/kh are first written):
    u16* wc1t  = qh;                        // Wc1^T bf16, 2*M1
    u16* wc2_b = kh;                        // Wc2 bf16, 2*M1

    // ---- weight prep ----
    cvt_kernel<<<6 * M1 / 1024, 256, 0, stream>>>(Wqkv, wqkv_b, (int)(6 * M1 / 4));
    cvt_kernel<<<2 * M1 / 1024, 256, 0, stream>>>(Wo,   wo_b,   (int)(2 * M1 / 4));
    cvt_kernel<<<M1 / 1024, 256, 0, stream>>>(Wfc, wfc_b, (int)(M1 / 4));
    cvt_kernel<<<2 * M1 / 1024, 256, 0, stream>>>(Wc2, wc2_b, (int)(2 * M1 / 4));
    cvtT_kernel<<<dim3(16, 16, 2), 256, 0, stream>>>(Wc1, wc1t);
    hipMemsetAsync(zb, 0, 1024 * 4, stream);
    gemm_z2<<<dim3(8, 8, 2), 256, 0, stream>>>(
        wc2_b, wc1t, zb, wcomb, 1.f,
        wc2_b + M1, wc1t + M1, zb, wcomb + M1, 1.f);
    matvec_kernel<<<512, 256, 0, stream>>>(Wc2, bc1, bc2, bcomb);
    mask_kernel<<<32768, 256, 0, stream>>>(amask, maskw);
    rowflag_kernel<<<32, 256, 0, stream>>>(maskw, rowfl);

    dim3 g8(8192 / 256, 1024 / 128);    // (32, 8) standard
    dim3 v8(1024 / 256, 8192 / 128);    // (4, 64) swapped V-projection
    dim3 gqk(8192 / 256, 1024 / 256, 2); // (32, 4, 2) paired Q+K 256^2
    const float QS = 0.125f * 1.44269504f;   // (1/sqrt(dk)) * log2(e): exp2-domain scores
    const int D = 1024;
    for (int i = 0; i < 2; ++i) {
        // LN1 -> t0 (bf16)
        if (i == 0) {
            ln_f<<<2048, 256, 0, stream>>>(q_in, ln1g, ln1b, t0);
            cvt_kernel<<<8192, 256, 0, stream>>>(k_in, x2, (int)(MT / 4));
            cvt_kernel<<<8192, 256, 0, stream>>>(v_in, xb, (int)(MT / 4));
        } else {
            ln_b<<<2048, 256, 0, stream>>>(x2, ln1g + i * D, ln1b + i * D, t0);
        }
        // Q (prescaled into exp2 domain) and K projections, paired 256^2 kernel
        gemm_qk256<<<gqk, 512, 0, stream>>>(
            t0, wqkv_b + (size_t)(i * 3 + 0) * M1, bqkv + (i * 3 + 0) * D, qh, QS,
            x2, wqkv_b + (size_t)(i * 3 + 1) * M1, bqkv + (i * 3 + 1) * D, kh, 1.f);
        // V projection, swapped: vt[d][s] = W_v · X^T  (row-bias)
        const u16* vin_b = (i == 0) ? xb : x2;
        gemm8<8 | 16, 8192><<<v8, 512, 0, stream>>>(wqkv_b + (size_t)(i * 3 + 2) * M1, vin_b,
                                                    bqkv + (i * 3 + 2) * D, nullptr, nullptr, vt, 1.f);
        // attention -> t0
        attn_kernel<<<dim3(128, 8), 512, 0, stream>>>(qh, kh, vt, maskw, rowfl, t0);
        // t1 = f2b(k_state + relu(attn @ Wo^T + bo))   (bf16 residual)
        gemm8<1 | 2 | 8, 1024><<<g8, 512, 0, stream>>>(t0, wo_b + (size_t)i * M1,
                                                       bo + i * D, x2, nullptr, t1, 1.f);
        // k1 = LN2(t1) -> xb (bf16)
        ln_b<<<2048, 256, 0, stream>>>(t1, ln2g + i * D, ln2b + i * D, xb);
        // folded FFN: x2 = f2b(k1 + k1 @ Wcomb^T + bcomb)   (res = xb itself)
        gemm8<2 | 8, 1024><<<g8, 512, 0, stream>>>(xb, wcomb + (size_t)i * M1,
                                                   bcomb + i * 1024, xb, nullptr, x2, 1.f);
    }
    // final LN + FC
    ln_b<<<2048, 256, 0, stream>>>(x2, lastg, lastb, t0);
    gemm8<4, 1024><<<g8, 512, 0, stream>>>(t0, wfc_b, bfc, nullptr, out, nullptr, 1.f);
}